// Round 9
// baseline (1164.221 us; speedup 1.0000x reference)
//
#include <hip/hip_runtime.h>
#include <hip/hip_bf16.h>
#include <math.h>

static constexpr int Bv = 2, Tv = 1024, Dv = 768, Hv = 12, Lv = 6, Vv = 32000, HDv = 64;
static constexpr int MROWS = Bv * Tv;   // 2048

typedef __attribute__((ext_vector_type(8))) short bf16x8;
typedef __attribute__((ext_vector_type(8))) short short8;
typedef __attribute__((ext_vector_type(4))) short short4v;
typedef __attribute__((ext_vector_type(4))) float f32x4;

typedef __attribute__((address_space(1))) const void gvoid;
typedef __attribute__((address_space(3))) void svoid;
__device__ __forceinline__ void gld16(const void* g, void* s) {
  __builtin_amdgcn_global_load_lds((gvoid*)g, (svoid*)s, 16, 0, 0);
}
__device__ __forceinline__ short f2bf(float v) {
  __hip_bfloat16 hb = __float2bfloat16(v);
  return *reinterpret_cast<short*>(&hb);
}
// bijective XCD-chunk remap (m204)
__device__ __forceinline__ int xcd_remap(int lin, int nwg) {
  int q = nwg >> 3, r = nwg & 7;
  int xcd = lin & 7, idx = lin >> 3;
  return (xcd < r ? xcd * (q + 1) : r * (q + 1) + (xcd - r) * q) + idx;
}

// ---------------- embedding body ----------------
__device__ __forceinline__ void embed_body(const int* __restrict__ idx,
                                           const float* __restrict__ wte,
                                           const float* __restrict__ wpe,
                                           float* __restrict__ x, int blk) {
  int i4 = blk * 256 + threadIdx.x;
  int total = MROWS * Dv / 4;
  if (i4 >= total) return;
  int d4 = (i4 % (Dv / 4)) * 4;
  int bt = i4 / (Dv / 4);
  int t  = bt % Tv;
  int id = idx[bt];
  float4 a = *(const float4*)(wte + (size_t)id * Dv + d4);
  float4 p = *(const float4*)(wpe + (size_t)t  * Dv + d4);
  a.x += p.x; a.y += p.y; a.z += p.z; a.w += p.w;
  *(float4*)(x + (size_t)bt * Dv + d4) = a;
}

__global__ __launch_bounds__(256) void embed_kernel(const int* __restrict__ idx,
                                                    const float* __restrict__ wte,
                                                    const float* __restrict__ wpe,
                                                    float* __restrict__ x) {
  embed_body(idx, wte, wpe, x, blockIdx.x);
}

// ---------------- layernorm: fp32 in -> bf16 out ----------------
__global__ __launch_bounds__(256) void ln_kernel(const float* __restrict__ x,
                                                 const float* __restrict__ w,
                                                 const float* __restrict__ b,
                                                 __hip_bfloat16* __restrict__ out) {
  int row = blockIdx.x;
  const float* xr = x + (size_t)row * Dv;
  int tid = threadIdx.x;
  float v0 = xr[tid], v1 = xr[tid + 256], v2 = xr[tid + 512];
  __shared__ float red[8];
  int wid = tid >> 6, lane = tid & 63;

  float s = v0 + v1 + v2;
  #pragma unroll
  for (int off = 1; off < 64; off <<= 1) s += __shfl_xor(s, off, 64);
  if (lane == 0) red[wid] = s;
  __syncthreads();
  s = red[0] + red[1] + red[2] + red[3];
  float mu = s * (1.0f / Dv);

  float d0 = v0 - mu, d1 = v1 - mu, d2 = v2 - mu;
  float q = d0 * d0 + d1 * d1 + d2 * d2;
  #pragma unroll
  for (int off = 1; off < 64; off <<= 1) q += __shfl_xor(q, off, 64);
  if (lane == 0) red[4 + wid] = q;
  __syncthreads();
  q = red[4] + red[5] + red[6] + red[7];
  float rs = rsqrtf(q * (1.0f / Dv) + 1e-5f);

  __hip_bfloat16* orow = out + (size_t)row * Dv;
  orow[tid]       = __float2bfloat16(d0 * rs * w[tid]       + b[tid]);
  orow[tid + 256] = __float2bfloat16(d1 * rs * w[tid + 256] + b[tid + 256]);
  orow[tid + 512] = __float2bfloat16(d2 * rs * w[tid + 512] + b[tid + 512]);
}

// ---------------- transpose+cast body ----------------
__device__ __forceinline__ void tcast_body(const float* __restrict__ W,
                                           __hip_bfloat16* __restrict__ Wt,
                                           int K, int N, int k0, int n0) {
  __shared__ float tile[32][33];
  int tx = threadIdx.x & 31, ty = threadIdx.x >> 5;
  #pragma unroll
  for (int r = 0; r < 32; r += 8)
    tile[ty + r][tx] = W[(size_t)(k0 + ty + r) * N + n0 + tx];
  __syncthreads();
  #pragma unroll
  for (int r = 0; r < 32; r += 8)
    Wt[(size_t)(n0 + ty + r) * K + k0 + tx] = __float2bfloat16(tile[tx][ty + r]);
}

__global__ __launch_bounds__(256) void tcast_kernel(const float* __restrict__ W,
                                                    __hip_bfloat16* __restrict__ Wt,
                                                    int K, int N) {
  tcast_body(W, Wt, K, N, blockIdx.y * 32, blockIdx.x * 32);
}

__global__ __launch_bounds__(256) void tcast4_kernel(const float* __restrict__ s0,
                                                     const float* __restrict__ s1,
                                                     const float* __restrict__ s2,
                                                     const float* __restrict__ s3,
                                                     __hip_bfloat16* __restrict__ d0,
                                                     __hip_bfloat16* __restrict__ d1,
                                                     __hip_bfloat16* __restrict__ d2,
                                                     __hip_bfloat16* __restrict__ d3) {
  int lin = blockIdx.x;
  const float* W; __hip_bfloat16* Wt; int K, N, loc;
  if (lin < 1728)      { W = s0; Wt = d0; K = 768;  N = 2304; loc = lin; }
  else if (lin < 2304) { W = s1; Wt = d1; K = 768;  N = 768;  loc = lin - 1728; }
  else if (lin < 4608) { W = s2; Wt = d2; K = 768;  N = 3072; loc = lin - 2304; }
  else                 { W = s3; Wt = d3; K = 3072; N = 768;  loc = lin - 4608; }
  int nb = N / 32;
  tcast_body(W, Wt, K, N, (loc / nb) * 32, (loc % nb) * 32);
}

// ---------------- one-shot prestage: embed + ALL weight tcasts ------------
// blocks: [0,1536) embed; then per-range weight tiles (see decode).
__global__ __launch_bounds__(256) void prestage_kernel(const int* __restrict__ idx,
                                                       const float* __restrict__ wte,
                                                       const float* __restrict__ wpe,
                                                       float* __restrict__ x,
                                                       const float* __restrict__ attn_w,
                                                       const float* __restrict__ proj_w,
                                                       const float* __restrict__ fc_w,
                                                       const float* __restrict__ fcproj_w,
                                                       const float* __restrict__ head_w,
                                                       __hip_bfloat16* __restrict__ wb_attn,
                                                       __hip_bfloat16* __restrict__ wb_proj,
                                                       __hip_bfloat16* __restrict__ wb_fc,
                                                       __hip_bfloat16* __restrict__ wb_fcproj,
                                                       __hip_bfloat16* __restrict__ wb_head) {
  int lin = blockIdx.x;
  if (lin < 1536) { embed_body(idx, wte, wpe, x, lin); return; }
  int t = lin - 1536;
  const float* W; __hip_bfloat16* Wt; int K, N, loc;
  if (t < 10368) {                   // attn: 6 x 1728
    int l = t / 1728; loc = t % 1728; K = 768; N = 2304;
    W = attn_w + (size_t)l * 768 * 2304; Wt = wb_attn + (size_t)l * 768 * 2304;
  } else if (t < 13824) {            // proj: 6 x 576
    int t2 = t - 10368; int l = t2 / 576; loc = t2 % 576; K = 768; N = 768;
    W = proj_w + (size_t)l * 768 * 768; Wt = wb_proj + (size_t)l * 768 * 768;
  } else if (t < 27648) {            // fc: 6 x 2304
    int t3 = t - 13824; int l = t3 / 2304; loc = t3 % 2304; K = 768; N = 3072;
    W = fc_w + (size_t)l * 768 * 3072; Wt = wb_fc + (size_t)l * 768 * 3072;
  } else if (t < 41472) {            // fcproj: 6 x 2304
    int t4 = t - 27648; int l = t4 / 2304; loc = t4 % 2304; K = 3072; N = 768;
    W = fcproj_w + (size_t)l * 3072 * 768; Wt = wb_fcproj + (size_t)l * 3072 * 768;
  } else {                           // head: 24000
    loc = t - 41472; K = 768; N = 32000;
    W = head_w; Wt = wb_head;
  }
  int nb = N / 32;
  tcast_body(W, Wt, K, N, (loc / nb) * 32, (loc % nb) * 32);
}

// ---------------- 128x128 MFMA GEMM body: BK=64, XOR swizzle, 2-phase dbuf --
template <bool GELU, bool OBF, bool VT>
__device__ __forceinline__ void gemm128_body(const __hip_bfloat16* __restrict__ A,
                                             const __hip_bfloat16* __restrict__ Wt,
                                             const float* __restrict__ bias,
                                             const float* __restrict__ resid,
                                             void* __restrict__ outv,
                                             __hip_bfloat16* __restrict__ vt,
                                             int M, int N, int K) {
  __shared__ short As[2][8192];   // [128][64] per buf, XOR-swizzled granules
  __shared__ short Bs[2][8192];
  int nwg = gridDim.x * gridDim.y;
  int wgid = xcd_remap(blockIdx.y * gridDim.x + blockIdx.x, nwg);
  int m0 = (wgid % gridDim.x) * 128, n0 = (wgid / gridDim.x) * 128;

  int tid = threadIdx.x;
  int w = tid >> 6, lane = tid & 63;
  int wr = w >> 1, wc = w & 1;
  int lr = lane & 15, lk = lane >> 4;

  f32x4 acc[4][4];
  #pragma unroll
  for (int m = 0; m < 4; ++m)
    #pragma unroll
    for (int n = 0; n < 4; ++n) acc[m][n] = (f32x4){0.f, 0.f, 0.f, 0.f};

  auto stg = [&](int k0, int p) {
    #pragma unroll
    for (int e = 0; e < 4; ++e) {
      int idx2 = e * 256 + tid;
      int r = idx2 >> 3, g = idx2 & 7;
      int gs = (g ^ (r & 7)) * 8;               // pre-swizzled global granule
      gld16(A  + (size_t)(m0 + r) * K + k0 + gs, &As[p][idx2 * 8]);
      gld16(Wt + (size_t)(n0 + r) * K + k0 + gs, &Bs[p][idx2 * 8]);
    }
  };

  stg(0, 0);
  __syncthreads();
  int NK = K >> 6;
  for (int kt = 0; kt < NK; ++kt) {
    int p = kt & 1;
    if (kt + 1 < NK) stg((kt + 1) << 6, p ^ 1);
    bf16x8 af[4][2], bf[4][2];
    #pragma unroll
    for (int m = 0; m < 4; ++m) {
      int ra = wr * 64 + m * 16 + lr;
      #pragma unroll
      for (int kf = 0; kf < 2; ++kf)
        af[m][kf] = *(const bf16x8*)(&As[p][ra * 64 + (((kf * 4 + lk) ^ (ra & 7)) * 8)]);
    }
    #pragma unroll
    for (int n = 0; n < 4; ++n) {
      int rb = wc * 64 + n * 16 + lr;
      #pragma unroll
      for (int kf = 0; kf < 2; ++kf)
        bf[n][kf] = *(const bf16x8*)(&Bs[p][rb * 64 + (((kf * 4 + lk) ^ (rb & 7)) * 8)]);
    }
    #pragma unroll
    for (int kf = 0; kf < 2; ++kf)
      #pragma unroll
      for (int m = 0; m < 4; ++m)
        #pragma unroll
        for (int n = 0; n < 4; ++n)
          acc[m][n] = __builtin_amdgcn_mfma_f32_16x16x32_bf16(af[m][kf], bf[n][kf], acc[m][n], 0, 0, 0);
    __syncthreads();   // drains stage vmcnt + publishes next buf
  }

  int row0 = m0 + wr * 64, col0 = n0 + wc * 64;
  float* outf = (float*)outv;
  __hip_bfloat16* outb = (__hip_bfloat16*)outv;
  #pragma unroll
  for (int n = 0; n < 4; ++n) {
    int col = col0 + n * 16 + lr;
    float bv = bias ? bias[col] : 0.f;
    #pragma unroll
    for (int m = 0; m < 4; ++m) {
      int rbase = row0 + m * 16 + lk * 4;
      float r4[4];
      #pragma unroll
      for (int j = 0; j < 4; ++j) {
        float v = acc[m][n][j] + bv;
        if (GELU) v = 0.5f * v * (1.0f + erff(v * 0.70710678118f));
        size_t o = (size_t)(rbase + j) * N + col;
        if (resid) v += resid[o];
        r4[j] = v;
        if (OBF) outb[o] = __float2bfloat16(v);
        else     outf[o] = v;
      }
      if (VT && col >= 2 * Dv) {
        int hh = (col - 2 * Dv) >> 6, dd = (col - 2 * Dv) & 63;
        int bb = rbase >> 10, t0 = rbase & 1023;
        short4v pk = {f2bf(r4[0]), f2bf(r4[1]), f2bf(r4[2]), f2bf(r4[3])};
        *(short4v*)(vt + (((size_t)(bb * Hv + hh) * HDv + dd) << 10) + t0) = pk;
      }
    }
  }
}

__global__ __launch_bounds__(256) void qkv_gemm_kernel(const __hip_bfloat16* A,
                                                       const __hip_bfloat16* Wt,
                                                       const float* bias,
                                                       void* outv, __hip_bfloat16* vt,
                                                       int M, int N, int K) {
  gemm128_body<false, true, true>(A, Wt, bias, nullptr, outv, vt, M, N, K);
}
__global__ __launch_bounds__(256) void fc_gemm_kernel(const __hip_bfloat16* A,
                                                      const __hip_bfloat16* Wt,
                                                      const float* bias,
                                                      void* outv, int M, int N, int K) {
  gemm128_body<true, true, false>(A, Wt, bias, nullptr, outv, nullptr, M, N, K);
}

// ---------------- 64x64 MFMA GEMM body (BK=64, swizzled, 2-phase dbuf) -----
__device__ __forceinline__ void gemm64_body(const __hip_bfloat16* __restrict__ A,
                                            const __hip_bfloat16* __restrict__ Wt,
                                            const float* __restrict__ bias,
                                            const float* __restrict__ resid,
                                            float* __restrict__ out,
                                            int M, int N, int K) {
  __shared__ short As[2][4096];
  __shared__ short Bs[2][4096];
  int nwg = gridDim.x * gridDim.y;
  int wgid = xcd_remap(blockIdx.y * gridDim.x + blockIdx.x, nwg);
  int m0 = (wgid % gridDim.x) * 64, n0 = (wgid / gridDim.x) * 64;

  int tid = threadIdx.x;
  int w = tid >> 6, lane = tid & 63;
  int wr = w >> 1, wc = w & 1;
  int lr = lane & 15, lk = lane >> 4;
  int rsub = lane >> 3, go = lane & 7;

  f32x4 acc[2][2];
  #pragma unroll
  for (int m = 0; m < 2; ++m)
    #pragma unroll
    for (int n = 0; n < 2; ++n) acc[m][n] = (f32x4){0.f, 0.f, 0.f, 0.f};

  auto stg = [&](int k0, int p) {
    #pragma unroll
    for (int e = 0; e < 2; ++e) {
      int row = w * 16 + e * 8 + rsub;
      int gs = (go ^ rsub) * 8;
      gld16(A  + (size_t)(m0 + row) * K + k0 + gs, &As[p][w * 1024 + e * 512]);
      gld16(Wt + (size_t)(n0 + row) * K + k0 + gs, &Bs[p][w * 1024 + e * 512]);
    }
  };

  stg(0, 0);
  __syncthreads();
  int NK = K >> 6;
  for (int kt = 0; kt < NK; ++kt) {
    int p = kt & 1;
    if (kt + 1 < NK) stg((kt + 1) << 6, p ^ 1);
    #pragma unroll
    for (int kf = 0; kf < 2; ++kf) {
      bf16x8 af[2], bf[2];
      #pragma unroll
      for (int m = 0; m < 2; ++m) {
        int row = wr * 32 + m * 16 + lr;
        af[m] = *(const bf16x8*)(&As[p][row * 64 + (((kf * 4 + lk) ^ (row & 7)) * 8)]);
      }
      #pragma unroll
      for (int n = 0; n < 2; ++n) {
        int row = wc * 32 + n * 16 + lr;
        bf[n] = *(const bf16x8*)(&Bs[p][row * 64 + (((kf * 4 + lk) ^ (row & 7)) * 8)]);
      }
      #pragma unroll
      for (int m = 0; m < 2; ++m)
        #pragma unroll
        for (int n = 0; n < 2; ++n)
          acc[m][n] = __builtin_amdgcn_mfma_f32_16x16x32_bf16(af[m], bf[n], acc[m][n], 0, 0, 0);
    }
    __syncthreads();
  }

  int row0 = m0 + wr * 32, col0 = n0 + wc * 32;
  #pragma unroll
  for (int n = 0; n < 2; ++n) {
    int col = col0 + n * 16 + lr;
    float bv = bias ? bias[col] : 0.f;
    #pragma unroll
    for (int m = 0; m < 2; ++m) {
      int rbase = row0 + m * 16 + lk * 4;
      #pragma unroll
      for (int j = 0; j < 4; ++j) {
        float v = acc[m][n][j] + bv;
        size_t o = (size_t)(rbase + j) * N + col;
        if (resid) v += resid[o];
        out[o] = v;
      }
    }
  }
}

__global__ __launch_bounds__(256) void proj_gemm_kernel(const __hip_bfloat16* A,
                                                        const __hip_bfloat16* Wt,
                                                        const float* bias,
                                                        const float* resid, float* out,
                                                        int M, int N, int K) {
  gemm64_body(A, Wt, bias, resid, out, M, N, K);
}
__global__ __launch_bounds__(256) void fcproj_gemm_kernel(const __hip_bfloat16* A,
                                                          const __hip_bfloat16* Wt,
                                                          const float* bias,
                                                          const float* resid, float* out,
                                                          int M, int N, int K) {
  gemm64_body(A, Wt, bias, resid, out, M, N, K);
}

// ---------------- 256x256 4-phase counted-vmcnt GEMM (head) ---------------
// Round-6 proven schedule: prologue vmcnt(4)+barrier, loop vmcnt(4), phantom
// stages keep the ledger uniform through the final tile. Invariant: each
// half's per-wave retire happens >=1 phase (with a barrier) before first read.
__global__ __launch_bounds__(512, 2) void gemm256_kernel(const __hip_bfloat16* __restrict__ A,
                                                         const __hip_bfloat16* __restrict__ Wt,
                                                         float* __restrict__ out,
                                                         int N, int K) {
  __shared__ short lds[65536];   // 128 KB
  int nwg = gridDim.x * gridDim.y;
  int wgid = xcd_remap(blockIdx.y * gridDim.x + blockIdx.x, nwg);
  int m0 = (wgid % gridDim.x) * 256, n0 = (wgid / gridDim.x) * 256;

  int tid = threadIdx.x;
  int w = tid >> 6, lane = tid & 63;
  int wr = w >> 2, wc = w & 3;          // 2 x 4 waves
  int lr = lane & 15, lk = lane >> 4;

  f32x4 acc[8][4];
  #pragma unroll
  for (int m = 0; m < 8; ++m)
    #pragma unroll
    for (int n = 0; n < 4; ++n) acc[m][n] = (f32x4){0.f, 0.f, 0.f, 0.f};

  int NT = K >> 6;

  auto stage = [&](int tau, int h) {
    int tsrc = tau < NT ? tau : NT - 1;       // phantom: re-read last tile
    const __hip_bfloat16* mat;
    size_t rb; int lofs;
    if (h == 0)      { mat = A;  rb = (size_t)m0;       lofs = 0; }
    else if (h == 1) { mat = Wt; rb = (size_t)n0;       lofs = 16384; }
    else if (h == 2) { mat = Wt; rb = (size_t)n0 + 128; lofs = 24576; }
    else             { mat = A;  rb = (size_t)m0 + 128; lofs = 8192; }
    short* lb = lds + (tau & 1) * 32768 + lofs;   // parity of REQUESTED tile
    #pragma unroll
    for (int e = 0; e < 2; ++e) {
      int idx = e * 512 + tid;
      int r = idx >> 3, g = idx & 7;
      gld16(mat + (rb + r) * (size_t)K + tsrc * 64 + ((g ^ (r & 7)) * 8), lb + idx * 8);
    }
  };

  stage(0, 0); stage(0, 1); stage(0, 2); stage(0, 3);
  asm volatile("s_waitcnt vmcnt(4)" ::: "memory");
  asm volatile("s_barrier" ::: "memory");

  for (int tau = 0; tau < NT; ++tau) {
    const short* bufA = lds + (tau & 1) * 32768;
    const short* bufB = bufA + 16384;
    #pragma unroll
    for (int q = 0; q < 4; ++q) {
      stage(tau + 1, q);
      asm volatile("s_waitcnt vmcnt(4)" ::: "memory");
      int qm = q >> 1, qn = q & 1;
      const short* ab = bufA + qm * 8192;
      const short* bb = bufB + qn * 8192;
      bf16x8 af[4][2], bf[2][2];
      #pragma unroll
      for (int mi = 0; mi < 4; ++mi) {
        int ra = wr * 64 + mi * 16 + lr;
        #pragma unroll
        for (int kf = 0; kf < 2; ++kf)
          af[mi][kf] = *(const bf16x8*)(ab + ra * 64 + (((kf * 4 + lk) ^ (ra & 7)) * 8));
      }
      #pragma unroll
      for (int ni = 0; ni < 2; ++ni) {
        int rb2 = wc * 32 + ni * 16 + lr;
        #pragma unroll
        for (int kf = 0; kf < 2; ++kf)
          bf[ni][kf] = *(const bf16x8*)(bb + rb2 * 64 + (((kf * 4 + lk) ^ (rb2 & 7)) * 8));
      }
      asm volatile("s_barrier" ::: "memory");
      __builtin_amdgcn_s_setprio(1);
      #pragma unroll
      for (int mi = 0; mi < 4; ++mi)
        #pragma unroll
        for (int ni = 0; ni < 2; ++ni)
          #pragma unroll
          for (int kf = 0; kf < 2; ++kf)
            acc[qm * 4 + mi][qn * 2 + ni] = __builtin_amdgcn_mfma_f32_16x16x32_bf16(
                af[mi][kf], bf[ni][kf], acc[qm * 4 + mi][qn * 2 + ni], 0, 0, 0);
      __builtin_amdgcn_s_setprio(0);
      asm volatile("s_barrier" ::: "memory");
    }
  }

  #pragma unroll
  for (int gm = 0; gm < 8; ++gm) {
    int row = m0 + (gm >> 2) * 128 + wr * 64 + (gm & 3) * 16 + lk * 4;
    #pragma unroll
    for (int gn = 0; gn < 4; ++gn) {
      int col = n0 + (gn >> 1) * 128 + wc * 32 + (gn & 1) * 16 + lr;
      #pragma unroll
      for (int j = 0; j < 4; ++j)
        out[(size_t)(row + j) * N + col] = acc[gm][gn][j];
    }
  }
}

// ---------------- MFMA flash attention (K/V dbuf + setprio) ----------------
__global__ __launch_bounds__(256) void attn_kernel(const __hip_bfloat16* __restrict__ qkv,
                                                   const __hip_bfloat16* __restrict__ vt,
                                                   __hip_bfloat16* __restrict__ y) {
  __shared__ short Ks[2][4096];
  __shared__ short Vts[2][4096];
  __shared__ short Ps[4][1024];
  int b = blockIdx.z, h = blockIdx.y;
  int qb = (gridDim.x - 1 - blockIdx.x) * 64;
  int tid = threadIdx.x;
  int w = tid >> 6, l = tid & 63;
  int lr = l & 15, lk = l >> 4;

  bf16x8 aq[2];
  {
    const __hip_bfloat16* qp = qkv + ((size_t)(b * Tv + qb + w * 16 + lr)) * 3 * Dv + h * HDv + lk * 8;
    aq[0] = *(const bf16x8*)qp;
    aq[1] = *(const bf16x8*)(qp + 32);
  }

  f32x4 o[4];
  #pragma unroll
  for (int n = 0; n < 4; ++n) o[n] = (f32x4){0.f, 0.f, 0.f, 0.f};
  float mrow[4] = {-1e30f, -1e30f, -1e30f, -1e30f};
  float lrow[4] = {0.f, 0.f, 0.f, 0.f};

  int r8 = l >> 3, c8 = l & 7;
  int nt = qb / 64 + 1;

  auto stageKV = [&](int kt2, int p) {
    int kbase = kt2 * 64;
    #pragma unroll
    for (int e = 0; e < 2; ++e) {
      int r0 = w * 16 + e * 8;
      int rK = r0 + r8;
      int csK = c8 ^ (rK & 7);
      gld16(qkv + ((size_t)(b * Tv + kbase + rK)) * 3 * Dv + Dv + h * HDv + csK * 8,
            &Ks[p][r0 * 64]);
      gld16(vt + ((size_t)((b * Hv + h) * HDv + rK)) * Tv + kbase + csK * 8,
            &Vts[p][r0 * 64]);
    }
  };

  stageKV(0, 0);
  __syncthreads();

  for (int kt = 0; kt < nt; ++kt) {
    int p = kt & 1;
    if (kt + 1 < nt) stageKV(kt + 1, p ^ 1);

    f32x4 s[4];
    #pragma unroll
    for (int n = 0; n < 4; ++n) s[n] = (f32x4){0.f, 0.f, 0.f, 0.f};
    __builtin_amdgcn_s_setprio(1);
    #pragma unroll
    for (int kf = 0; kf < 2; ++kf)
      #pragma unroll
      for (int nf = 0; nf < 4; ++nf) {
        int row = nf * 16 + lr;
        int g = (kf * 4 + lk) ^ (row & 7);
        bf16x8 bk = *(const bf16x8*)(&Ks[p][row * 64 + g * 8]);
        s[nf] = __builtin_amdgcn_mfma_f32_16x16x32_bf16(aq[kf], bk, s[nf], 0, 0, 0);
      }
    __builtin_amdgcn_s_setprio(0);
    #pragma unroll
    for (int nf = 0; nf < 4; ++nf)
      #pragma unroll
      for (int j = 0; j < 4; ++j) s[nf][j] *= 0.125f;

    if (kt == nt - 1) {
      #pragma unroll
      for (int nf = 0; nf < 4; ++nf) {
        int kl = nf * 16 + lr;
        #pragma unroll
        for (int j = 0; j < 4; ++j)
          if (kl > w * 16 + lk * 4 + j) s[nf][j] = -1e30f;
      }
    }

    float sc[4];
    #pragma unroll
    for (int j = 0; j < 4; ++j) {
      float pm = fmaxf(fmaxf(s[0][j], s[1][j]), fmaxf(s[2][j], s[3][j]));
      pm = fmaxf(pm, __shfl_xor(pm, 1, 64));
      pm = fmaxf(pm, __shfl_xor(pm, 2, 64));
      pm = fmaxf(pm, __shfl_xor(pm, 4, 64));
      pm = fmaxf(pm, __shfl_xor(pm, 8, 64));
      float mn = fmaxf(mrow[j], pm);
      sc[j] = __expf(mrow[j] - mn);
      mrow[j] = mn;
    }
    #pragma unroll
    for (int j = 0; j < 4; ++j) {
      float ls = 0.f;
      #pragma unroll
      for (int nf = 0; nf < 4; ++nf) {
        float p2 = __expf(s[nf][j] - mrow[j]);
        s[nf][j] = p2;
        ls += p2;
      }
      ls += __shfl_xor(ls, 1, 64);
      ls += __shfl_xor(ls, 2, 64);
      ls += __shfl_xor(ls, 4, 64);
      ls += __shfl_xor(ls, 8, 64);
      lrow[j] = lrow[j] * sc[j] + ls;
    }
    #pragma unroll
    for (int n = 0; n < 4; ++n)
      #pragma unroll
      for (int j = 0; j < 4; ++j) o[n][j] *= sc[j];

    short* pw = Ps[w];
    #pragma unroll
    for (int nf = 0; nf < 4; ++nf)
      #pragma unroll
      for (int j = 0; j < 4; ++j) {
        int ql = lk * 4 + j, k = nf * 16 + lr;
        pw[ql * 64 + (((k >> 3) ^ (ql & 7)) * 8) + (k & 7)] = f2bf(s[nf][j]);
      }
    bf16x8 pa[2];
    #pragma unroll
    for (int kf = 0; kf < 2; ++kf) {
      int g = (kf * 4 + lk) ^ (lr & 7);
      pa[kf] = *(const bf16x8*)(pw + lr * 64 + g * 8);
    }
    __builtin_amdgcn_s_setprio(1);
    #pragma unroll
    for (int kf = 0; kf < 2; ++kf)
      #pragma unroll
      for (int nf = 0; nf < 4; ++nf) {
        int d = nf * 16 + lr;
        int g = (kf * 4 + lk) ^ (d & 7);
        bf16x8 bv = *(const bf16x8*)(&Vts[p][d * 64 + g * 8]);
        o[nf] = __builtin_amdgcn_mfma_f32_16x16x32_bf16(pa[kf], bv, o[nf], 0, 0, 0);
      }
    __builtin_amdgcn_s_setprio(0);
    __syncthreads();   // drains next-tile stage + WAR for buf p
  }

  #pragma unroll
  for (int j = 0; j < 4; ++j) lrow[j] = 1.f / lrow[j];
  #pragma unroll
  for (int nf = 0; nf < 4; ++nf)
    #pragma unroll
    for (int j = 0; j < 4; ++j) {
      size_t oidx = ((size_t)(b * Tv + qb + w * 16 + lk * 4 + j)) * Dv + h * HDv + nf * 16 + lr;
      y[oidx] = __float2bfloat16(o[nf][j] * lrow[j]);
    }
}

extern "C" void kernel_launch(void* const* d_in, const int* in_sizes, int n_in,
                              void* d_out, int out_size, void* d_ws, size_t ws_size,
                              hipStream_t stream) {
  const int*   idx      = (const int*)  d_in[0];
  const float* wte      = (const float*)d_in[1];
  const float* wpe      = (const float*)d_in[2];
  const float* ln1_w    = (const float*)d_in[3];
  const float* ln1_b    = (const float*)d_in[4];
  const float* attn_w   = (const float*)d_in[5];
  const float* attn_b   = (const float*)d_in[6];
  const float* proj_w   = (const float*)d_in[7];
  const float* proj_b   = (const float*)d_in[8];
  const float* ln2_w    = (const float*)d_in[9];
  const float* ln2_b    = (const float*)d_in[10];
  const float* fc_w     = (const float*)d_in[11];
  const float* fc_b     = (const float*)d_in[12];
  const float* fcproj_w = (const float*)d_in[13];
  const float* fcproj_b = (const float*)d_in[14];
  const float* lnf_w    = (const float*)d_in[15];
  const float* lnf_b    = (const float*)d_in[16];
  const float* head_w   = (const float*)d_in[17];
  float* outp = (float*)d_out;

  char* w8 = (char*)d_ws;
  float*          x    = (float*)w8;                          // 2048*768 f32
  __hip_bfloat16* h    = (__hip_bfloat16*)(w8 + 6291456);     // 2048*768 bf16
  __hip_bfloat16* qkv  = (__hip_bfloat16*)(w8 + 9437184);     // 2048*2304 bf16
  __hip_bfloat16* m4   = qkv;                                 // 2048*3072 bf16 alias
  __hip_bfloat16* y    = (__hip_bfloat16*)(w8 + 22020096);    // 2048*768 bf16
  __hip_bfloat16* vt   = (__hip_bfloat16*)(w8 + 25165824);    // B*H*64*1024 bf16
  __hip_bfloat16* wbuf = (__hip_bfloat16*)(w8 + 28311552);    // weight staging

  // prestaged layout (needs 162,398,208 B)
  bool big = ws_size >= 162398208ull;
  __hip_bfloat16* wa_attn   = wbuf;                                 // 6*768*2304
  __hip_bfloat16* wa_proj   = wa_attn   + (size_t)6 * 768 * 2304;   // 6*768*768
  __hip_bfloat16* wa_fc     = wa_proj   + (size_t)6 * 768 * 768;    // 6*768*3072
  __hip_bfloat16* wa_fcproj = wa_fc     + (size_t)6 * 768 * 3072;   // 6*3072*768
  __hip_bfloat16* wa_head   = wa_fcproj + (size_t)6 * 3072 * 768;   // 32000*768

  if (big) {
    prestage_kernel<<<67008, 256, 0, stream>>>(
        idx, wte, wpe, x, attn_w, proj_w, fc_w, fcproj_w, head_w,
        wa_attn, wa_proj, wa_fc, wa_fcproj, wa_head);

    for (int l = 0; l < Lv; ++l) {
      ln_kernel<<<MROWS, 256, 0, stream>>>(x, ln1_w + (size_t)l * Dv, ln1_b + (size_t)l * Dv, h);
      qkv_gemm_kernel<<<dim3(MROWS / 128, 3 * Dv / 128), 256, 0, stream>>>(
          h, wa_attn + (size_t)l * 768 * 2304, attn_b + (size_t)l * 3 * Dv, qkv, vt, MROWS, 3 * Dv, Dv);
      attn_kernel<<<dim3(Tv / 64, Hv, Bv), 256, 0, stream>>>(qkv, vt, y);
      proj_gemm_kernel<<<dim3(MROWS / 64, Dv / 64), 256, 0, stream>>>(
          y, wa_proj + (size_t)l * 768 * 768, proj_b + (size_t)l * Dv, x, x, MROWS, Dv, Dv);
      ln_kernel<<<MROWS, 256, 0, stream>>>(x, ln2_w + (size_t)l * Dv, ln2_b + (size_t)l * Dv, h);
      fc_gemm_kernel<<<dim3(MROWS / 128, 4 * Dv / 128), 256, 0, stream>>>(
          h, wa_fc + (size_t)l * 768 * 3072, fc_b + (size_t)l * 4 * Dv, m4, MROWS, 4 * Dv, Dv);
      fcproj_gemm_kernel<<<dim3(MROWS / 64, Dv / 64), 256, 0, stream>>>(
          m4, wa_fcproj + (size_t)l * 3072 * 768, fcproj_b + (size_t)l * Dv, x, x, MROWS, Dv, 4 * Dv);
    }

    ln_kernel<<<MROWS, 256, 0, stream>>>(x, lnf_w, lnf_b, h);
    gemm256_kernel<<<dim3(MROWS / 256, Vv / 256), 512, 0, stream>>>(
        h, wa_head, outp, Vv, Dv);
    return;
  }

  // ---------------- fallback: per-layer staging (round-8 path) ----------------
  __hip_bfloat16* wb_attn   = wbuf;
  __hip_bfloat16* wb_proj   = wb_attn + (size_t)768 * 2304;
  __hip_bfloat16* wb_fc     = wb_proj + (size_t)768 * 768;
  __hip_bfloat16* wb_fcproj = wb_fc   + (size_t)768 * 3072;

  embed_kernel<<<(MROWS * Dv / 4 + 255) / 256, 256, 0, stream>>>(idx, wte, wpe, x);

  for (int l = 0; l < Lv; ++l) {
    ln_kernel<<<MROWS, 256, 0, stream>>>(x, ln1_w + (size_t)l * Dv, ln1_b + (size_t)l * Dv, h);
    tcast4_kernel<<<6912, 256, 0, stream>>>(
        attn_w   + (size_t)l * Dv * 3 * Dv,
        proj_w   + (size_t)l * Dv * Dv,
        fc_w     + (size_t)l * Dv * 4 * Dv,
        fcproj_w + (size_t)l * 4 * Dv * Dv,
        wb_attn, wb_proj, wb_fc, wb_fcproj);
    qkv_gemm_kernel<<<dim3(MROWS / 128, 3 * Dv / 128), 256, 0, stream>>>(
        h, wb_attn, attn_b + (size_t)l * 3 * Dv, qkv, vt, MROWS, 3 * Dv, Dv);
    attn_kernel<<<dim3(Tv / 64, Hv, Bv), 256, 0, stream>>>(qkv, vt, y);
    proj_gemm_kernel<<<dim3(MROWS / 64, Dv / 64), 256, 0, stream>>>(
        y, wb_proj, proj_b + (size_t)l * Dv, x, x, MROWS, Dv, Dv);
    ln_kernel<<<MROWS, 256, 0, stream>>>(x, ln2_w + (size_t)l * Dv, ln2_b + (size_t)l * Dv, h);
    fc_gemm_kernel<<<dim3(MROWS / 128, 4 * Dv / 128), 256, 0, stream>>>(
        h, wb_fc, fc_b + (size_t)l * 4 * Dv, m4, MROWS, 4 * Dv, Dv);
    fcproj_gemm_kernel<<<dim3(MROWS / 64, Dv / 64), 256, 0, stream>>>(
        m4, wb_fcproj, fcproj_b + (size_t)l * Dv, x, x, MROWS, Dv, 4 * Dv);
  }

  ln_kernel<<<MROWS, 256, 0, stream>>>(x, lnf_w, lnf_b, h);
  tcast_kernel<<<dim3(Vv / 32, Dv / 32), 256, 0, stream>>>(head_w, wbuf, Dv, Vv);
  gemm256_kernel<<<dim3(MROWS / 256, Vv / 256), 512, 0, stream>>>(
      h, wbuf, outp, Vv, Dv);
}

// Round 10
// 1101.514 us; speedup vs baseline: 1.0569x; 1.0569x over previous
//
#include <hip/hip_runtime.h>
#include <hip/hip_bf16.h>
#include <math.h>

static constexpr int Bv = 2, Tv = 1024, Dv = 768, Hv = 12, Lv = 6, Vv = 32000, HDv = 64;
static constexpr int MROWS = Bv * Tv;   // 2048

typedef __attribute__((ext_vector_type(8))) short bf16x8;
typedef __attribute__((ext_vector_type(8))) short short8;
typedef __attribute__((ext_vector_type(4))) short short4v;
typedef __attribute__((ext_vector_type(4))) float f32x4;

typedef __attribute__((address_space(1))) const void gvoid;
typedef __attribute__((address_space(3))) void svoid;
__device__ __forceinline__ void gld16(const void* g, void* s) {
  __builtin_amdgcn_global_load_lds((gvoid*)g, (svoid*)s, 16, 0, 0);
}
__device__ __forceinline__ short f2bf(float v) {
  __hip_bfloat16 hb = __float2bfloat16(v);
  return *reinterpret_cast<short*>(&hb);
}
// bijective XCD-chunk remap (m204)
__device__ __forceinline__ int xcd_remap(int lin, int nwg) {
  int q = nwg >> 3, r = nwg & 7;
  int xcd = lin & 7, idx = lin >> 3;
  return (xcd < r ? xcd * (q + 1) : r * (q + 1) + (xcd - r) * q) + idx;
}

// ---------------- embedding ----------------
__global__ __launch_bounds__(256) void embed_kernel(const int* __restrict__ idx,
                                                    const float* __restrict__ wte,
                                                    const float* __restrict__ wpe,
                                                    float* __restrict__ x) {
  int i4 = blockIdx.x * 256 + threadIdx.x;
  int total = MROWS * Dv / 4;
  if (i4 >= total) return;
  int d4 = (i4 % (Dv / 4)) * 4;
  int bt = i4 / (Dv / 4);
  int t  = bt % Tv;
  int id = idx[bt];
  float4 a = *(const float4*)(wte + (size_t)id * Dv + d4);
  float4 p = *(const float4*)(wpe + (size_t)t  * Dv + d4);
  a.x += p.x; a.y += p.y; a.z += p.z; a.w += p.w;
  *(float4*)(x + (size_t)bt * Dv + d4) = a;
}

// ---------------- layernorm: fp32 in -> bf16 out ----------------
__global__ __launch_bounds__(256) void ln_kernel(const float* __restrict__ x,
                                                 const float* __restrict__ w,
                                                 const float* __restrict__ b,
                                                 __hip_bfloat16* __restrict__ out) {
  int row = blockIdx.x;
  const float* xr = x + (size_t)row * Dv;
  int tid = threadIdx.x;
  float v0 = xr[tid], v1 = xr[tid + 256], v2 = xr[tid + 512];
  __shared__ float red[8];
  int wid = tid >> 6, lane = tid & 63;

  float s = v0 + v1 + v2;
  #pragma unroll
  for (int off = 1; off < 64; off <<= 1) s += __shfl_xor(s, off, 64);
  if (lane == 0) red[wid] = s;
  __syncthreads();
  s = red[0] + red[1] + red[2] + red[3];
  float mu = s * (1.0f / Dv);

  float d0 = v0 - mu, d1 = v1 - mu, d2 = v2 - mu;
  float q = d0 * d0 + d1 * d1 + d2 * d2;
  #pragma unroll
  for (int off = 1; off < 64; off <<= 1) q += __shfl_xor(q, off, 64);
  if (lane == 0) red[4 + wid] = q;
  __syncthreads();
  q = red[4] + red[5] + red[6] + red[7];
  float rs = rsqrtf(q * (1.0f / Dv) + 1e-5f);

  __hip_bfloat16* orow = out + (size_t)row * Dv;
  orow[tid]       = __float2bfloat16(d0 * rs * w[tid]       + b[tid]);
  orow[tid + 256] = __float2bfloat16(d1 * rs * w[tid + 256] + b[tid + 256]);
  orow[tid + 512] = __float2bfloat16(d2 * rs * w[tid + 512] + b[tid + 512]);
}

// ---------------- transpose+cast body ----------------
__device__ __forceinline__ void tcast_body(const float* __restrict__ W,
                                           __hip_bfloat16* __restrict__ Wt,
                                           int K, int N, int k0, int n0) {
  __shared__ float tile[32][33];
  int tx = threadIdx.x & 31, ty = threadIdx.x >> 5;
  #pragma unroll
  for (int r = 0; r < 32; r += 8)
    tile[ty + r][tx] = W[(size_t)(k0 + ty + r) * N + n0 + tx];
  __syncthreads();
  #pragma unroll
  for (int r = 0; r < 32; r += 8)
    Wt[(size_t)(n0 + ty + r) * K + k0 + tx] = __float2bfloat16(tile[tx][ty + r]);
}

__global__ __launch_bounds__(256) void tcast_kernel(const float* __restrict__ W,
                                                    __hip_bfloat16* __restrict__ Wt,
                                                    int K, int N) {
  tcast_body(W, Wt, K, N, blockIdx.y * 32, blockIdx.x * 32);
}

__global__ __launch_bounds__(256) void tcast4_kernel(const float* __restrict__ s0,
                                                     const float* __restrict__ s1,
                                                     const float* __restrict__ s2,
                                                     const float* __restrict__ s3,
                                                     __hip_bfloat16* __restrict__ d0,
                                                     __hip_bfloat16* __restrict__ d1,
                                                     __hip_bfloat16* __restrict__ d2,
                                                     __hip_bfloat16* __restrict__ d3) {
  int lin = blockIdx.x;
  const float* W; __hip_bfloat16* Wt; int K, N, loc;
  if (lin < 1728)      { W = s0; Wt = d0; K = 768;  N = 2304; loc = lin; }
  else if (lin < 2304) { W = s1; Wt = d1; K = 768;  N = 768;  loc = lin - 1728; }
  else if (lin < 4608) { W = s2; Wt = d2; K = 768;  N = 3072; loc = lin - 2304; }
  else                 { W = s3; Wt = d3; K = 3072; N = 768;  loc = lin - 4608; }
  int nb = N / 32;
  tcast_body(W, Wt, K, N, (loc / nb) * 32, (loc % nb) * 32);
}

// ---------------- 128x128 MFMA GEMM body: BK=64, XOR swizzle, 2-phase dbuf --
// 64KB LDS -> 2 blocks/CU: one block's epilogue stores overlap the other's
// MFMA phase (why this beats the 128KB 256^2 kernel for the store-heavy head).
template <bool GELU, bool OBF, bool VT>
__device__ __forceinline__ void gemm128_body(const __hip_bfloat16* __restrict__ A,
                                             const __hip_bfloat16* __restrict__ Wt,
                                             const float* __restrict__ bias,
                                             const float* __restrict__ resid,
                                             void* __restrict__ outv,
                                             __hip_bfloat16* __restrict__ vt,
                                             int M, int N, int K) {
  __shared__ short As[2][8192];   // [128][64] per buf, XOR-swizzled granules
  __shared__ short Bs[2][8192];
  int nwg = gridDim.x * gridDim.y;
  int wgid = xcd_remap(blockIdx.y * gridDim.x + blockIdx.x, nwg);
  int m0 = (wgid % gridDim.x) * 128, n0 = (wgid / gridDim.x) * 128;

  int tid = threadIdx.x;
  int w = tid >> 6, lane = tid & 63;
  int wr = w >> 1, wc = w & 1;
  int lr = lane & 15, lk = lane >> 4;

  f32x4 acc[4][4];
  #pragma unroll
  for (int m = 0; m < 4; ++m)
    #pragma unroll
    for (int n = 0; n < 4; ++n) acc[m][n] = (f32x4){0.f, 0.f, 0.f, 0.f};

  auto stg = [&](int k0, int p) {
    #pragma unroll
    for (int e = 0; e < 4; ++e) {
      int idx2 = e * 256 + tid;
      int r = idx2 >> 3, g = idx2 & 7;
      int gs = (g ^ (r & 7)) * 8;               // pre-swizzled global granule
      gld16(A  + (size_t)(m0 + r) * K + k0 + gs, &As[p][idx2 * 8]);
      gld16(Wt + (size_t)(n0 + r) * K + k0 + gs, &Bs[p][idx2 * 8]);
    }
  };

  stg(0, 0);
  __syncthreads();
  int NK = K >> 6;
  for (int kt = 0; kt < NK; ++kt) {
    int p = kt & 1;
    if (kt + 1 < NK) stg((kt + 1) << 6, p ^ 1);
    bf16x8 af[4][2], bf[4][2];
    #pragma unroll
    for (int m = 0; m < 4; ++m) {
      int ra = wr * 64 + m * 16 + lr;
      #pragma unroll
      for (int kf = 0; kf < 2; ++kf)
        af[m][kf] = *(const bf16x8*)(&As[p][ra * 64 + (((kf * 4 + lk) ^ (ra & 7)) * 8)]);
    }
    #pragma unroll
    for (int n = 0; n < 4; ++n) {
      int rb = wc * 64 + n * 16 + lr;
      #pragma unroll
      for (int kf = 0; kf < 2; ++kf)
        bf[n][kf] = *(const bf16x8*)(&Bs[p][rb * 64 + (((kf * 4 + lk) ^ (rb & 7)) * 8)]);
    }
    #pragma unroll
    for (int kf = 0; kf < 2; ++kf)
      #pragma unroll
      for (int m = 0; m < 4; ++m)
        #pragma unroll
        for (int n = 0; n < 4; ++n)
          acc[m][n] = __builtin_amdgcn_mfma_f32_16x16x32_bf16(af[m][kf], bf[n][kf], acc[m][n], 0, 0, 0);
    __syncthreads();   // drains stage vmcnt + publishes next buf
  }

  int row0 = m0 + wr * 64, col0 = n0 + wc * 64;
  float* outf = (float*)outv;
  __hip_bfloat16* outb = (__hip_bfloat16*)outv;
  #pragma unroll
  for (int n = 0; n < 4; ++n) {
    int col = col0 + n * 16 + lr;
    float bv = bias ? bias[col] : 0.f;
    #pragma unroll
    for (int m = 0; m < 4; ++m) {
      int rbase = row0 + m * 16 + lk * 4;
      float r4[4];
      #pragma unroll
      for (int j = 0; j < 4; ++j) {
        float v = acc[m][n][j] + bv;
        if (GELU) v = 0.5f * v * (1.0f + erff(v * 0.70710678118f));
        size_t o = (size_t)(rbase + j) * N + col;
        if (resid) v += resid[o];
        r4[j] = v;
        if (OBF) outb[o] = __float2bfloat16(v);
        else     outf[o] = v;
      }
      if (VT && col >= 2 * Dv) {
        int hh = (col - 2 * Dv) >> 6, dd = (col - 2 * Dv) & 63;
        int bb = rbase >> 10, t0 = rbase & 1023;
        short4v pk = {f2bf(r4[0]), f2bf(r4[1]), f2bf(r4[2]), f2bf(r4[3])};
        *(short4v*)(vt + (((size_t)(bb * Hv + hh) * HDv + dd) << 10) + t0) = pk;
      }
    }
  }
}

__global__ __launch_bounds__(256) void qkv_gemm_kernel(const __hip_bfloat16* A,
                                                       const __hip_bfloat16* Wt,
                                                       const float* bias,
                                                       void* outv, __hip_bfloat16* vt,
                                                       int M, int N, int K) {
  gemm128_body<false, true, true>(A, Wt, bias, nullptr, outv, vt, M, N, K);
}
__global__ __launch_bounds__(256) void fc_gemm_kernel(const __hip_bfloat16* A,
                                                      const __hip_bfloat16* Wt,
                                                      const float* bias,
                                                      void* outv, int M, int N, int K) {
  gemm128_body<true, true, false>(A, Wt, bias, nullptr, outv, nullptr, M, N, K);
}
__global__ __launch_bounds__(256) void head_gemm_kernel(const __hip_bfloat16* A,
                                                        const __hip_bfloat16* Wt,
                                                        void* outv, int M, int N, int K) {
  gemm128_body<false, false, false>(A, Wt, nullptr, nullptr, outv, nullptr, M, N, K);
}

// ---------------- 64x64 MFMA GEMM body (BK=64, swizzled, 2-phase dbuf) -----
__device__ __forceinline__ void gemm64_body(const __hip_bfloat16* __restrict__ A,
                                            const __hip_bfloat16* __restrict__ Wt,
                                            const float* __restrict__ bias,
                                            const float* __restrict__ resid,
                                            float* __restrict__ out,
                                            int M, int N, int K) {
  __shared__ short As[2][4096];
  __shared__ short Bs[2][4096];
  int nwg = gridDim.x * gridDim.y;
  int wgid = xcd_remap(blockIdx.y * gridDim.x + blockIdx.x, nwg);
  int m0 = (wgid % gridDim.x) * 64, n0 = (wgid / gridDim.x) * 64;

  int tid = threadIdx.x;
  int w = tid >> 6, lane = tid & 63;
  int wr = w >> 1, wc = w & 1;
  int lr = lane & 15, lk = lane >> 4;
  int rsub = lane >> 3, go = lane & 7;

  f32x4 acc[2][2];
  #pragma unroll
  for (int m = 0; m < 2; ++m)
    #pragma unroll
    for (int n = 0; n < 2; ++n) acc[m][n] = (f32x4){0.f, 0.f, 0.f, 0.f};

  auto stg = [&](int k0, int p) {
    #pragma unroll
    for (int e = 0; e < 2; ++e) {
      int row = w * 16 + e * 8 + rsub;
      int gs = (go ^ rsub) * 8;
      gld16(A  + (size_t)(m0 + row) * K + k0 + gs, &As[p][w * 1024 + e * 512]);
      gld16(Wt + (size_t)(n0 + row) * K + k0 + gs, &Bs[p][w * 1024 + e * 512]);
    }
  };

  stg(0, 0);
  __syncthreads();
  int NK = K >> 6;
  for (int kt = 0; kt < NK; ++kt) {
    int p = kt & 1;
    if (kt + 1 < NK) stg((kt + 1) << 6, p ^ 1);
    #pragma unroll
    for (int kf = 0; kf < 2; ++kf) {
      bf16x8 af[2], bf[2];
      #pragma unroll
      for (int m = 0; m < 2; ++m) {
        int row = wr * 32 + m * 16 + lr;
        af[m] = *(const bf16x8*)(&As[p][row * 64 + (((kf * 4 + lk) ^ (row & 7)) * 8)]);
      }
      #pragma unroll
      for (int n = 0; n < 2; ++n) {
        int row = wc * 32 + n * 16 + lr;
        bf[n] = *(const bf16x8*)(&Bs[p][row * 64 + (((kf * 4 + lk) ^ (row & 7)) * 8)]);
      }
      #pragma unroll
      for (int m = 0; m < 2; ++m)
        #pragma unroll
        for (int n = 0; n < 2; ++n)
          acc[m][n] = __builtin_amdgcn_mfma_f32_16x16x32_bf16(af[m], bf[n], acc[m][n], 0, 0, 0);
    }
    __syncthreads();
  }

  int row0 = m0 + wr * 32, col0 = n0 + wc * 32;
  #pragma unroll
  for (int n = 0; n < 2; ++n) {
    int col = col0 + n * 16 + lr;
    float bv = bias ? bias[col] : 0.f;
    #pragma unroll
    for (int m = 0; m < 2; ++m) {
      int rbase = row0 + m * 16 + lk * 4;
      #pragma unroll
      for (int j = 0; j < 4; ++j) {
        float v = acc[m][n][j] + bv;
        size_t o = (size_t)(rbase + j) * N + col;
        if (resid) v += resid[o];
        out[o] = v;
      }
    }
  }
}

__global__ __launch_bounds__(256) void proj_gemm_kernel(const __hip_bfloat16* A,
                                                        const __hip_bfloat16* Wt,
                                                        const float* bias,
                                                        const float* resid, float* out,
                                                        int M, int N, int K) {
  gemm64_body(A, Wt, bias, resid, out, M, N, K);
}
__global__ __launch_bounds__(256) void fcproj_gemm_kernel(const __hip_bfloat16* A,
                                                          const __hip_bfloat16* Wt,
                                                          const float* bias,
                                                          const float* resid, float* out,
                                                          int M, int N, int K) {
  gemm64_body(A, Wt, bias, resid, out, M, N, K);
}

// ---------------- MFMA flash attention (K/V dbuf + setprio) ----------------
__global__ __launch_bounds__(256) void attn_kernel(const __hip_bfloat16* __restrict__ qkv,
                                                   const __hip_bfloat16* __restrict__ vt,
                                                   __hip_bfloat16* __restrict__ y) {
  __shared__ short Ks[2][4096];
  __shared__ short Vts[2][4096];
  __shared__ short Ps[4][1024];
  int b = blockIdx.z, h = blockIdx.y;
  int qb = (gridDim.x - 1 - blockIdx.x) * 64;
  int tid = threadIdx.x;
  int w = tid >> 6, l = tid & 63;
  int lr = l & 15, lk = l >> 4;

  bf16x8 aq[2];
  {
    const __hip_bfloat16* qp = qkv + ((size_t)(b * Tv + qb + w * 16 + lr)) * 3 * Dv + h * HDv + lk * 8;
    aq[0] = *(const bf16x8*)qp;
    aq[1] = *(const bf16x8*)(qp + 32);
  }

  f32x4 o[4];
  #pragma unroll
  for (int n = 0; n < 4; ++n) o[n] = (f32x4){0.f, 0.f, 0.f, 0.f};
  float mrow[4] = {-1e30f, -1e30f, -1e30f, -1e30f};
  float lrow[4] = {0.f, 0.f, 0.f, 0.f};

  int r8 = l >> 3, c8 = l & 7;
  int nt = qb / 64 + 1;

  auto stageKV = [&](int kt2, int p) {
    int kbase = kt2 * 64;
    #pragma unroll
    for (int e = 0; e < 2; ++e) {
      int r0 = w * 16 + e * 8;
      int rK = r0 + r8;
      int csK = c8 ^ (rK & 7);
      gld16(qkv + ((size_t)(b * Tv + kbase + rK)) * 3 * Dv + Dv + h * HDv + csK * 8,
            &Ks[p][r0 * 64]);
      gld16(vt + ((size_t)((b * Hv + h) * HDv + rK)) * Tv + kbase + csK * 8,
            &Vts[p][r0 * 64]);
    }
  };

  stageKV(0, 0);
  __syncthreads();

  for (int kt = 0; kt < nt; ++kt) {
    int p = kt & 1;
    if (kt + 1 < nt) stageKV(kt + 1, p ^ 1);

    f32x4 s[4];
    #pragma unroll
    for (int n = 0; n < 4; ++n) s[n] = (f32x4){0.f, 0.f, 0.f, 0.f};
    __builtin_amdgcn_s_setprio(1);
    #pragma unroll
    for (int kf = 0; kf < 2; ++kf)
      #pragma unroll
      for (int nf = 0; nf < 4; ++nf) {
        int row = nf * 16 + lr;
        int g = (kf * 4 + lk) ^ (row & 7);
        bf16x8 bk = *(const bf16x8*)(&Ks[p][row * 64 + g * 8]);
        s[nf] = __builtin_amdgcn_mfma_f32_16x16x32_bf16(aq[kf], bk, s[nf], 0, 0, 0);
      }
    __builtin_amdgcn_s_setprio(0);
    #pragma unroll
    for (int nf = 0; nf < 4; ++nf)
      #pragma unroll
      for (int j = 0; j < 4; ++j) s[nf][j] *= 0.125f;

    if (kt == nt - 1) {
      #pragma unroll
      for (int nf = 0; nf < 4; ++nf) {
        int kl = nf * 16 + lr;
        #pragma unroll
        for (int j = 0; j < 4; ++j)
          if (kl > w * 16 + lk * 4 + j) s[nf][j] = -1e30f;
      }
    }

    float sc[4];
    #pragma unroll
    for (int j = 0; j < 4; ++j) {
      float pm = fmaxf(fmaxf(s[0][j], s[1][j]), fmaxf(s[2][j], s[3][j]));
      pm = fmaxf(pm, __shfl_xor(pm, 1, 64));
      pm = fmaxf(pm, __shfl_xor(pm, 2, 64));
      pm = fmaxf(pm, __shfl_xor(pm, 4, 64));
      pm = fmaxf(pm, __shfl_xor(pm, 8, 64));
      float mn = fmaxf(mrow[j], pm);
      sc[j] = __expf(mrow[j] - mn);
      mrow[j] = mn;
    }
    #pragma unroll
    for (int j = 0; j < 4; ++j) {
      float ls = 0.f;
      #pragma unroll
      for (int nf = 0; nf < 4; ++nf) {
        float p2 = __expf(s[nf][j] - mrow[j]);
        s[nf][j] = p2;
        ls += p2;
      }
      ls += __shfl_xor(ls, 1, 64);
      ls += __shfl_xor(ls, 2, 64);
      ls += __shfl_xor(ls, 4, 64);
      ls += __shfl_xor(ls, 8, 64);
      lrow[j] = lrow[j] * sc[j] + ls;
    }
    #pragma unroll
    for (int n = 0; n < 4; ++n)
      #pragma unroll
      for (int j = 0; j < 4; ++j) o[n][j] *= sc[j];

    short* pw = Ps[w];
    #pragma unroll
    for (int nf = 0; nf < 4; ++nf)
      #pragma unroll
      for (int j = 0; j < 4; ++j) {
        int ql = lk * 4 + j, k = nf * 16 + lr;
        pw[ql * 64 + (((k >> 3) ^ (ql & 7)) * 8) + (k & 7)] = f2bf(s[nf][j]);
      }
    bf16x8 pa[2];
    #pragma unroll
    for (int kf = 0; kf < 2; ++kf) {
      int g = (kf * 4 + lk) ^ (lr & 7);
      pa[kf] = *(const bf16x8*)(pw + lr * 64 + g * 8);
    }
    __builtin_amdgcn_s_setprio(1);
    #pragma unroll
    for (int kf = 0; kf < 2; ++kf)
      #pragma unroll
      for (int nf = 0; nf < 4; ++nf) {
        int d = nf * 16 + lr;
        int g = (kf * 4 + lk) ^ (d & 7);
        bf16x8 bv = *(const bf16x8*)(&Vts[p][d * 64 + g * 8]);
        o[nf] = __builtin_amdgcn_mfma_f32_16x16x32_bf16(pa[kf], bv, o[nf], 0, 0, 0);
      }
    __builtin_amdgcn_s_setprio(0);
    __syncthreads();   // drains next-tile stage + WAR for buf p
  }

  #pragma unroll
  for (int j = 0; j < 4; ++j) lrow[j] = 1.f / lrow[j];
  #pragma unroll
  for (int nf = 0; nf < 4; ++nf)
    #pragma unroll
    for (int j = 0; j < 4; ++j) {
      size_t oidx = ((size_t)(b * Tv + qb + w * 16 + lk * 4 + j)) * Dv + h * HDv + nf * 16 + lr;
      y[oidx] = __float2bfloat16(o[nf][j] * lrow[j]);
    }
}

extern "C" void kernel_launch(void* const* d_in, const int* in_sizes, int n_in,
                              void* d_out, int out_size, void* d_ws, size_t ws_size,
                              hipStream_t stream) {
  const int*   idx      = (const int*)  d_in[0];
  const float* wte      = (const float*)d_in[1];
  const float* wpe      = (const float*)d_in[2];
  const float* ln1_w    = (const float*)d_in[3];
  const float* ln1_b    = (const float*)d_in[4];
  const float* attn_w   = (const float*)d_in[5];
  const float* attn_b   = (const float*)d_in[6];
  const float* proj_w   = (const float*)d_in[7];
  const float* proj_b   = (const float*)d_in[8];
  const float* ln2_w    = (const float*)d_in[9];
  const float* ln2_b    = (const float*)d_in[10];
  const float* fc_w     = (const float*)d_in[11];
  const float* fc_b     = (const float*)d_in[12];
  const float* fcproj_w = (const float*)d_in[13];
  const float* fcproj_b = (const float*)d_in[14];
  const float* lnf_w    = (const float*)d_in[15];
  const float* lnf_b    = (const float*)d_in[16];
  const float* head_w   = (const float*)d_in[17];
  float* outp = (float*)d_out;

  char* w8 = (char*)d_ws;
  float*          x    = (float*)w8;                          // 2048*768 f32
  __hip_bfloat16* h    = (__hip_bfloat16*)(w8 + 6291456);     // 2048*768 bf16
  __hip_bfloat16* qkv  = (__hip_bfloat16*)(w8 + 9437184);     // 2048*2304 bf16
  __hip_bfloat16* m4   = qkv;                                 // 2048*3072 bf16 alias
  __hip_bfloat16* y    = (__hip_bfloat16*)(w8 + 22020096);    // 2048*768 bf16
  __hip_bfloat16* vt   = (__hip_bfloat16*)(w8 + 25165824);    // B*H*64*1024 bf16
  __hip_bfloat16* wbuf = (__hip_bfloat16*)(w8 + 28311552);    // weight staging

  __hip_bfloat16* wb_attn   = wbuf;
  __hip_bfloat16* wb_proj   = wb_attn + (size_t)768 * 2304;
  __hip_bfloat16* wb_fc     = wb_proj + (size_t)768 * 768;
  __hip_bfloat16* wb_fcproj = wb_fc   + (size_t)768 * 3072;

  embed_kernel<<<(MROWS * Dv / 4 + 255) / 256, 256, 0, stream>>>(idx, wte, wpe, x);

  for (int l = 0; l < Lv; ++l) {
    ln_kernel<<<MROWS, 256, 0, stream>>>(x, ln1_w + (size_t)l * Dv, ln1_b + (size_t)l * Dv, h);
    tcast4_kernel<<<6912, 256, 0, stream>>>(
        attn_w   + (size_t)l * Dv * 3 * Dv,
        proj_w   + (size_t)l * Dv * Dv,
        fc_w     + (size_t)l * Dv * 4 * Dv,
        fcproj_w + (size_t)l * 4 * Dv * Dv,
        wb_attn, wb_proj, wb_fc, wb_fcproj);
    qkv_gemm_kernel<<<dim3(MROWS / 128, 3 * Dv / 128), 256, 0, stream>>>(
        h, wb_attn, attn_b + (size_t)l * 3 * Dv, qkv, vt, MROWS, 3 * Dv, Dv);
    attn_kernel<<<dim3(Tv / 64, Hv, Bv), 256, 0, stream>>>(qkv, vt, y);
    proj_gemm_kernel<<<dim3(MROWS / 64, Dv / 64), 256, 0, stream>>>(
        y, wb_proj, proj_b + (size_t)l * Dv, x, x, MROWS, Dv, Dv);
    ln_kernel<<<MROWS, 256, 0, stream>>>(x, ln2_w + (size_t)l * Dv, ln2_b + (size_t)l * Dv, h);
    fc_gemm_kernel<<<dim3(MROWS / 128, 4 * Dv / 128), 256, 0, stream>>>(
        h, wb_fc, fc_b + (size_t)l * 4 * Dv, m4, MROWS, 4 * Dv, Dv);
    fcproj_gemm_kernel<<<dim3(MROWS / 64, Dv / 64), 256, 0, stream>>>(
        m4, wb_fcproj, fcproj_b + (size_t)l * Dv, x, x, MROWS, Dv, 4 * Dv);
  }

  ln_kernel<<<MROWS, 256, 0, stream>>>(x, lnf_w, lnf_b, h);
  tcast_kernel<<<dim3(Vv / 32, Dv / 32), 256, 0, stream>>>(head_w, wbuf, Dv, Vv);
  head_gemm_kernel<<<dim3(MROWS / 128, Vv / 128), 256, 0, stream>>>(
      h, wbuf, outp, MROWS, Vv, Dv);
}

// Round 11
// 1058.099 us; speedup vs baseline: 1.1003x; 1.0410x over previous
//
#include <hip/hip_runtime.h>
#include <hip/hip_bf16.h>
#include <math.h>

static constexpr int Bv = 2, Tv = 1024, Dv = 768, Hv = 12, Lv = 6, Vv = 32000, HDv = 64;
static constexpr int MROWS = Bv * Tv;   // 2048

typedef __attribute__((ext_vector_type(8))) short bf16x8;
typedef __attribute__((ext_vector_type(8))) short short8;
typedef __attribute__((ext_vector_type(4))) short short4v;
typedef __attribute__((ext_vector_type(4))) float f32x4;

typedef __attribute__((address_space(1))) const void gvoid;
typedef __attribute__((address_space(3))) void svoid;
__device__ __forceinline__ void gld16(const void* g, void* s) {
  __builtin_amdgcn_global_load_lds((gvoid*)g, (svoid*)s, 16, 0, 0);
}
__device__ __forceinline__ short f2bf(float v) {
  __hip_bfloat16 hb = __float2bfloat16(v);
  return *reinterpret_cast<short*>(&hb);
}
// bijective XCD-chunk remap (m204)
__device__ __forceinline__ int xcd_remap(int lin, int nwg) {
  int q = nwg >> 3, r = nwg & 7;
  int xcd = lin & 7, idx = lin >> 3;
  return (xcd < r ? xcd * (q + 1) : r * (q + 1) + (xcd - r) * q) + idx;
}

// ---------------- embedding ----------------
__global__ __launch_bounds__(256) void embed_kernel(const int* __restrict__ idx,
                                                    const float* __restrict__ wte,
                                                    const float* __restrict__ wpe,
                                                    float* __restrict__ x) {
  int i4 = blockIdx.x * 256 + threadIdx.x;
  int total = MROWS * Dv / 4;
  if (i4 >= total) return;
  int d4 = (i4 % (Dv / 4)) * 4;
  int bt = i4 / (Dv / 4);
  int t  = bt % Tv;
  int id = idx[bt];
  float4 a = *(const float4*)(wte + (size_t)id * Dv + d4);
  float4 p = *(const float4*)(wpe + (size_t)t  * Dv + d4);
  a.x += p.x; a.y += p.y; a.z += p.z; a.w += p.w;
  *(float4*)(x + (size_t)bt * Dv + d4) = a;
}

// ---------------- layernorm body: fp32 in -> bf16 out ----------------
__device__ __forceinline__ void ln_body(const float* __restrict__ x,
                                        const float* __restrict__ w,
                                        const float* __restrict__ b,
                                        __hip_bfloat16* __restrict__ out, int row) {
  __shared__ float red[8];
  const float* xr = x + (size_t)row * Dv;
  int tid = threadIdx.x;
  float v0 = xr[tid], v1 = xr[tid + 256], v2 = xr[tid + 512];
  int wid = tid >> 6, lane = tid & 63;

  float s = v0 + v1 + v2;
  #pragma unroll
  for (int off = 1; off < 64; off <<= 1) s += __shfl_xor(s, off, 64);
  if (lane == 0) red[wid] = s;
  __syncthreads();
  s = red[0] + red[1] + red[2] + red[3];
  float mu = s * (1.0f / Dv);

  float d0 = v0 - mu, d1 = v1 - mu, d2 = v2 - mu;
  float q = d0 * d0 + d1 * d1 + d2 * d2;
  #pragma unroll
  for (int off = 1; off < 64; off <<= 1) q += __shfl_xor(q, off, 64);
  if (lane == 0) red[4 + wid] = q;
  __syncthreads();
  q = red[4] + red[5] + red[6] + red[7];
  float rs = rsqrtf(q * (1.0f / Dv) + 1e-5f);

  __hip_bfloat16* orow = out + (size_t)row * Dv;
  orow[tid]       = __float2bfloat16(d0 * rs * w[tid]       + b[tid]);
  orow[tid + 256] = __float2bfloat16(d1 * rs * w[tid + 256] + b[tid + 256]);
  orow[tid + 512] = __float2bfloat16(d2 * rs * w[tid + 512] + b[tid + 512]);
}

__global__ __launch_bounds__(256) void ln_kernel(const float* __restrict__ x,
                                                 const float* __restrict__ w,
                                                 const float* __restrict__ b,
                                                 __hip_bfloat16* __restrict__ out) {
  ln_body(x, w, b, out, blockIdx.x);
}

// ---------------- transpose+cast body ----------------
__device__ __forceinline__ void tcast_body(const float* __restrict__ W,
                                           __hip_bfloat16* __restrict__ Wt,
                                           int K, int N, int k0, int n0) {
  __shared__ float tile[32][33];
  int tx = threadIdx.x & 31, ty = threadIdx.x >> 5;
  #pragma unroll
  for (int r = 0; r < 32; r += 8)
    tile[ty + r][tx] = W[(size_t)(k0 + ty + r) * N + n0 + tx];
  __syncthreads();
  #pragma unroll
  for (int r = 0; r < 32; r += 8)
    Wt[(size_t)(n0 + ty + r) * K + k0 + tx] = __float2bfloat16(tile[tx][ty + r]);
}

// ---------------- fused ln1 + 4-weight tcast (per layer) -------------------
// blocks [0,2048): ln rows; [2048,8960): tcast tiles (attn/proj/fc/fcproj).
__global__ __launch_bounds__(256) void ln_tcast4_kernel(const float* __restrict__ x,
                                                        const float* __restrict__ lw,
                                                        const float* __restrict__ lb,
                                                        __hip_bfloat16* __restrict__ h,
                                                        const float* __restrict__ s0,
                                                        const float* __restrict__ s1,
                                                        const float* __restrict__ s2,
                                                        const float* __restrict__ s3,
                                                        __hip_bfloat16* __restrict__ d0,
                                                        __hip_bfloat16* __restrict__ d1,
                                                        __hip_bfloat16* __restrict__ d2,
                                                        __hip_bfloat16* __restrict__ d3) {
  int blk = blockIdx.x;
  if (blk < MROWS) { ln_body(x, lw, lb, h, blk); return; }
  int lin = blk - MROWS;
  const float* W; __hip_bfloat16* Wt; int K, N, loc;
  if (lin < 1728)      { W = s0; Wt = d0; K = 768;  N = 2304; loc = lin; }
  else if (lin < 2304) { W = s1; Wt = d1; K = 768;  N = 768;  loc = lin - 1728; }
  else if (lin < 4608) { W = s2; Wt = d2; K = 768;  N = 3072; loc = lin - 2304; }
  else                 { W = s3; Wt = d3; K = 3072; N = 768;  loc = lin - 4608; }
  int nb = N / 32;
  tcast_body(W, Wt, K, N, (loc / nb) * 32, (loc % nb) * 32);
}

// ---------------- fused lnf + head tcast -----------------------------------
// blocks [0,2048): lnf rows; [2048,26048): head tcast tiles (768x32000).
__global__ __launch_bounds__(256) void lnf_tcast_kernel(const float* __restrict__ x,
                                                        const float* __restrict__ lw,
                                                        const float* __restrict__ lb,
                                                        __hip_bfloat16* __restrict__ h,
                                                        const float* __restrict__ head_w,
                                                        __hip_bfloat16* __restrict__ wb) {
  int blk = blockIdx.x;
  if (blk < MROWS) { ln_body(x, lw, lb, h, blk); return; }
  int loc = blk - MROWS;                 // 0..23999
  int nb = Vv / 32;                      // 1000
  tcast_body(head_w, wb, Dv, Vv, (loc / nb) * 32, (loc % nb) * 32);
}

// ---------------- 128x128 MFMA GEMM body: BK=64, XOR swizzle, 2-phase dbuf --
template <bool GELU, bool OBF, bool VT>
__device__ __forceinline__ void gemm128_body(const __hip_bfloat16* __restrict__ A,
                                             const __hip_bfloat16* __restrict__ Wt,
                                             const float* __restrict__ bias,
                                             const float* __restrict__ resid,
                                             void* __restrict__ outv,
                                             __hip_bfloat16* __restrict__ vt,
                                             int M, int N, int K) {
  __shared__ short As[2][8192];   // [128][64] per buf, XOR-swizzled granules
  __shared__ short Bs[2][8192];
  int nwg = gridDim.x * gridDim.y;
  int wgid = xcd_remap(blockIdx.y * gridDim.x + blockIdx.x, nwg);
  int m0 = (wgid % gridDim.x) * 128, n0 = (wgid / gridDim.x) * 128;

  int tid = threadIdx.x;
  int w = tid >> 6, lane = tid & 63;
  int wr = w >> 1, wc = w & 1;
  int lr = lane & 15, lk = lane >> 4;

  f32x4 acc[4][4];
  #pragma unroll
  for (int m = 0; m < 4; ++m)
    #pragma unroll
    for (int n = 0; n < 4; ++n) acc[m][n] = (f32x4){0.f, 0.f, 0.f, 0.f};

  auto stg = [&](int k0, int p) {
    #pragma unroll
    for (int e = 0; e < 4; ++e) {
      int idx2 = e * 256 + tid;
      int r = idx2 >> 3, g = idx2 & 7;
      int gs = (g ^ (r & 7)) * 8;               // pre-swizzled global granule
      gld16(A  + (size_t)(m0 + r) * K + k0 + gs, &As[p][idx2 * 8]);
      gld16(Wt + (size_t)(n0 + r) * K + k0 + gs, &Bs[p][idx2 * 8]);
    }
  };

  stg(0, 0);
  __syncthreads();
  int NK = K >> 6;
  for (int kt = 0; kt < NK; ++kt) {
    int p = kt & 1;
    if (kt + 1 < NK) stg((kt + 1) << 6, p ^ 1);
    bf16x8 af[4][2], bf[4][2];
    #pragma unroll
    for (int m = 0; m < 4; ++m) {
      int ra = wr * 64 + m * 16 + lr;
      #pragma unroll
      for (int kf = 0; kf < 2; ++kf)
        af[m][kf] = *(const bf16x8*)(&As[p][ra * 64 + (((kf * 4 + lk) ^ (ra & 7)) * 8)]);
    }
    #pragma unroll
    for (int n = 0; n < 4; ++n) {
      int rb = wc * 64 + n * 16 + lr;
      #pragma unroll
      for (int kf = 0; kf < 2; ++kf)
        bf[n][kf] = *(const bf16x8*)(&Bs[p][rb * 64 + (((kf * 4 + lk) ^ (rb & 7)) * 8)]);
    }
    #pragma unroll
    for (int kf = 0; kf < 2; ++kf)
      #pragma unroll
      for (int m = 0; m < 4; ++m)
        #pragma unroll
        for (int n = 0; n < 4; ++n)
          acc[m][n] = __builtin_amdgcn_mfma_f32_16x16x32_bf16(af[m][kf], bf[n][kf], acc[m][n], 0, 0, 0);
    __syncthreads();   // drains stage vmcnt + publishes next buf
  }

  int row0 = m0 + wr * 64, col0 = n0 + wc * 64;
  float* outf = (float*)outv;
  __hip_bfloat16* outb = (__hip_bfloat16*)outv;
  #pragma unroll
  for (int n = 0; n < 4; ++n) {
    int col = col0 + n * 16 + lr;
    float bv = bias ? bias[col] : 0.f;
    #pragma unroll
    for (int m = 0; m < 4; ++m) {
      int rbase = row0 + m * 16 + lk * 4;
      float r4[4];
      #pragma unroll
      for (int j = 0; j < 4; ++j) {
        float v = acc[m][n][j] + bv;
        if (GELU) v = 0.5f * v * (1.0f + erff(v * 0.70710678118f));
        size_t o = (size_t)(rbase + j) * N + col;
        if (resid) v += resid[o];
        r4[j] = v;
        if (OBF) outb[o] = __float2bfloat16(v);
        else     outf[o] = v;
      }
      if (VT && col >= 2 * Dv) {
        int hh = (col - 2 * Dv) >> 6, dd = (col - 2 * Dv) & 63;
        int bb = rbase >> 10, t0 = rbase & 1023;
        short4v pk = {f2bf(r4[0]), f2bf(r4[1]), f2bf(r4[2]), f2bf(r4[3])};
        *(short4v*)(vt + (((size_t)(bb * Hv + hh) * HDv + dd) << 10) + t0) = pk;
      }
    }
  }
}

__global__ __launch_bounds__(256) void qkv_gemm_kernel(const __hip_bfloat16* A,
                                                       const __hip_bfloat16* Wt,
                                                       const float* bias,
                                                       void* outv, __hip_bfloat16* vt,
                                                       int M, int N, int K) {
  gemm128_body<false, true, true>(A, Wt, bias, nullptr, outv, vt, M, N, K);
}
__global__ __launch_bounds__(256) void fc_gemm_kernel(const __hip_bfloat16* A,
                                                      const __hip_bfloat16* Wt,
                                                      const float* bias,
                                                      void* outv, int M, int N, int K) {
  gemm128_body<true, true, false>(A, Wt, bias, nullptr, outv, nullptr, M, N, K);
}

// ---------------- 64x64 MFMA GEMM body (BK=64, swizzled, 2-phase dbuf) -----
__device__ __forceinline__ void gemm64_body(const __hip_bfloat16* __restrict__ A,
                                            const __hip_bfloat16* __restrict__ Wt,
                                            const float* __restrict__ bias,
                                            const float* __restrict__ resid,
                                            float* __restrict__ out,
                                            int M, int N, int K) {
  __shared__ short As[2][4096];
  __shared__ short Bs[2][4096];
  int nwg = gridDim.x * gridDim.y;
  int wgid = xcd_remap(blockIdx.y * gridDim.x + blockIdx.x, nwg);
  int m0 = (wgid % gridDim.x) * 64, n0 = (wgid / gridDim.x) * 64;

  int tid = threadIdx.x;
  int w = tid >> 6, lane = tid & 63;
  int wr = w >> 1, wc = w & 1;
  int lr = lane & 15, lk = lane >> 4;
  int rsub = lane >> 3, go = lane & 7;

  f32x4 acc[2][2];
  #pragma unroll
  for (int m = 0; m < 2; ++m)
    #pragma unroll
    for (int n = 0; n < 2; ++n) acc[m][n] = (f32x4){0.f, 0.f, 0.f, 0.f};

  auto stg = [&](int k0, int p) {
    #pragma unroll
    for (int e = 0; e < 2; ++e) {
      int row = w * 16 + e * 8 + rsub;
      int gs = (go ^ rsub) * 8;
      gld16(A  + (size_t)(m0 + row) * K + k0 + gs, &As[p][w * 1024 + e * 512]);
      gld16(Wt + (size_t)(n0 + row) * K + k0 + gs, &Bs[p][w * 1024 + e * 512]);
    }
  };

  stg(0, 0);
  __syncthreads();
  int NK = K >> 6;
  for (int kt = 0; kt < NK; ++kt) {
    int p = kt & 1;
    if (kt + 1 < NK) stg((kt + 1) << 6, p ^ 1);
    #pragma unroll
    for (int kf = 0; kf < 2; ++kf) {
      bf16x8 af[2], bf[2];
      #pragma unroll
      for (int m = 0; m < 2; ++m) {
        int row = wr * 32 + m * 16 + lr;
        af[m] = *(const bf16x8*)(&As[p][row * 64 + (((kf * 4 + lk) ^ (row & 7)) * 8)]);
      }
      #pragma unroll
      for (int n = 0; n < 2; ++n) {
        int row = wc * 32 + n * 16 + lr;
        bf[n] = *(const bf16x8*)(&Bs[p][row * 64 + (((kf * 4 + lk) ^ (row & 7)) * 8)]);
      }
      #pragma unroll
      for (int m = 0; m < 2; ++m)
        #pragma unroll
        for (int n = 0; n < 2; ++n)
          acc[m][n] = __builtin_amdgcn_mfma_f32_16x16x32_bf16(af[m], bf[n], acc[m][n], 0, 0, 0);
    }
    __syncthreads();
  }

  int row0 = m0 + wr * 32, col0 = n0 + wc * 32;
  #pragma unroll
  for (int n = 0; n < 2; ++n) {
    int col = col0 + n * 16 + lr;
    float bv = bias ? bias[col] : 0.f;
    #pragma unroll
    for (int m = 0; m < 2; ++m) {
      int rbase = row0 + m * 16 + lk * 4;
      #pragma unroll
      for (int j = 0; j < 4; ++j) {
        float v = acc[m][n][j] + bv;
        size_t o = (size_t)(rbase + j) * N + col;
        if (resid) v += resid[o];
        out[o] = v;
      }
    }
  }
}

__global__ __launch_bounds__(256) void proj_gemm_kernel(const __hip_bfloat16* A,
                                                        const __hip_bfloat16* Wt,
                                                        const float* bias,
                                                        const float* resid, float* out,
                                                        int M, int N, int K) {
  gemm64_body(A, Wt, bias, resid, out, M, N, K);
}
__global__ __launch_bounds__(256) void fcproj_gemm_kernel(const __hip_bfloat16* A,
                                                          const __hip_bfloat16* Wt,
                                                          const float* bias,
                                                          const float* resid, float* out,
                                                          int M, int N, int K) {
  gemm64_body(A, Wt, bias, resid, out, M, N, K);
}

// ---------------- 256x256 4-phase counted-vmcnt GEMM (head) ---------------
// Round-6/8 proven schedule: prologue vmcnt(4)+barrier, loop vmcnt(4),
// phantom stages keep the ledger uniform through the final tile. Invariant:
// each half's per-wave retire happens >=1 phase (w/ barrier) before first read.
__global__ __launch_bounds__(512, 2) void gemm256_kernel(const __hip_bfloat16* __restrict__ A,
                                                         const __hip_bfloat16* __restrict__ Wt,
                                                         float* __restrict__ out,
                                                         int N, int K) {
  __shared__ short lds[65536];   // 128 KB
  int nwg = gridDim.x * gridDim.y;
  int wgid = xcd_remap(blockIdx.y * gridDim.x + blockIdx.x, nwg);
  int m0 = (wgid % gridDim.x) * 256, n0 = (wgid / gridDim.x) * 256;

  int tid = threadIdx.x;
  int w = tid >> 6, lane = tid & 63;
  int wr = w >> 2, wc = w & 3;          // 2 x 4 waves
  int lr = lane & 15, lk = lane >> 4;

  f32x4 acc[8][4];
  #pragma unroll
  for (int m = 0; m < 8; ++m)
    #pragma unroll
    for (int n = 0; n < 4; ++n) acc[m][n] = (f32x4){0.f, 0.f, 0.f, 0.f};

  int NT = K >> 6;

  auto stage = [&](int tau, int h) {
    int tsrc = tau < NT ? tau : NT - 1;       // phantom: re-read last tile
    const __hip_bfloat16* mat;
    size_t rb; int lofs;
    if (h == 0)      { mat = A;  rb = (size_t)m0;       lofs = 0; }
    else if (h == 1) { mat = Wt; rb = (size_t)n0;       lofs = 16384; }
    else if (h == 2) { mat = Wt; rb = (size_t)n0 + 128; lofs = 24576; }
    else             { mat = A;  rb = (size_t)m0 + 128; lofs = 8192; }
    short* lb = lds + (tau & 1) * 32768 + lofs;   // parity of REQUESTED tile
    #pragma unroll
    for (int e = 0; e < 2; ++e) {
      int idx = e * 512 + tid;
      int r = idx >> 3, g = idx & 7;
      gld16(mat + (rb + r) * (size_t)K + tsrc * 64 + ((g ^ (r & 7)) * 8), lb + idx * 8);
    }
  };

  stage(0, 0); stage(0, 1); stage(0, 2); stage(0, 3);
  asm volatile("s_waitcnt vmcnt(4)" ::: "memory");
  asm volatile("s_barrier" ::: "memory");

  for (int tau = 0; tau < NT; ++tau) {
    const short* bufA = lds + (tau & 1) * 32768;
    const short* bufB = bufA + 16384;
    #pragma unroll
    for (int q = 0; q < 4; ++q) {
      stage(tau + 1, q);
      asm volatile("s_waitcnt vmcnt(4)" ::: "memory");
      int qm = q >> 1, qn = q & 1;
      const short* ab = bufA + qm * 8192;
      const short* bb = bufB + qn * 8192;
      bf16x8 af[4][2], bf[2][2];
      #pragma unroll
      for (int mi = 0; mi < 4; ++mi) {
        int ra = wr * 64 + mi * 16 + lr;
        #pragma unroll
        for (int kf = 0; kf < 2; ++kf)
          af[mi][kf] = *(const bf16x8*)(ab + ra * 64 + (((kf * 4 + lk) ^ (ra & 7)) * 8));
      }
      #pragma unroll
      for (int ni = 0; ni < 2; ++ni) {
        int rb2 = wc * 32 + ni * 16 + lr;
        #pragma unroll
        for (int kf = 0; kf < 2; ++kf)
          bf[ni][kf] = *(const bf16x8*)(bb + rb2 * 64 + (((kf * 4 + lk) ^ (rb2 & 7)) * 8));
      }
      asm volatile("s_barrier" ::: "memory");
      __builtin_amdgcn_s_setprio(1);
      #pragma unroll
      for (int mi = 0; mi < 4; ++mi)
        #pragma unroll
        for (int ni = 0; ni < 2; ++ni)
          #pragma unroll
          for (int kf = 0; kf < 2; ++kf)
            acc[qm * 4 + mi][qn * 2 + ni] = __builtin_amdgcn_mfma_f32_16x16x32_bf16(
                af[mi][kf], bf[ni][kf], acc[qm * 4 + mi][qn * 2 + ni], 0, 0, 0);
      __builtin_amdgcn_s_setprio(0);
      asm volatile("s_barrier" ::: "memory");
    }
  }

  #pragma unroll
  for (int gm = 0; gm < 8; ++gm) {
    int row = m0 + (gm >> 2) * 128 + wr * 64 + (gm & 3) * 16 + lk * 4;
    #pragma unroll
    for (int gn = 0; gn < 4; ++gn) {
      int col = n0 + (gn >> 1) * 128 + wc * 32 + (gn & 1) * 16 + lr;
      #pragma unroll
      for (int j = 0; j < 4; ++j)
        out[(size_t)(row + j) * N + col] = acc[gm][gn][j];
    }
  }
}

// ---------------- MFMA flash attention (K/V dbuf + setprio) ----------------
__global__ __launch_bounds__(256) void attn_kernel(const __hip_bfloat16* __restrict__ qkv,
                                                   const __hip_bfloat16* __restrict__ vt,
                                                   __hip_bfloat16* __restrict__ y) {
  __shared__ short Ks[2][4096];
  __shared__ short Vts[2][4096];
  __shared__ short Ps[4][1024];
  int b = blockIdx.z, h = blockIdx.y;
  int qb = (gridDim.x - 1 - blockIdx.x) * 64;
  int tid = threadIdx.x;
  int w = tid >> 6, l = tid & 63;
  int lr = l & 15, lk = l >> 4;

  bf16x8 aq[2];
  {
    const __hip_bfloat16* qp = qkv + ((size_t)(b * Tv + qb + w * 16 + lr)) * 3 * Dv + h * HDv + lk * 8;
    aq[0] = *(const bf16x8*)qp;
    aq[1] = *(const bf16x8*)(qp + 32);
  }

  f32x4 o[4];
  #pragma unroll
  for (int n = 0; n < 4; ++n) o[n] = (f32x4){0.f, 0.f, 0.f, 0.f};
  float mrow[4] = {-1e30f, -1e30f, -1e30f, -1e30f};
  float lrow[4] = {0.f, 0.f, 0.f, 0.f};

  int r8 = l >> 3, c8 = l & 7;
  int nt = qb / 64 + 1;

  auto stageKV = [&](int kt2, int p) {
    int kbase = kt2 * 64;
    #pragma unroll
    for (int e = 0; e < 2; ++e) {
      int r0 = w * 16 + e * 8;
      int rK = r0 + r8;
      int csK = c8 ^ (rK & 7);
      gld16(qkv + ((size_t)(b * Tv + kbase + rK)) * 3 * Dv + Dv + h * HDv + csK * 8,
            &Ks[p][r0 * 64]);
      gld16(vt + ((size_t)((b * Hv + h) * HDv + rK)) * Tv + kbase + csK * 8,
            &Vts[p][r0 * 64]);
    }
  };

  stageKV(0, 0);
  __syncthreads();

  for (int kt = 0; kt < nt; ++kt) {
    int p = kt & 1;
    if (kt + 1 < nt) stageKV(kt + 1, p ^ 1);

    f32x4 s[4];
    #pragma unroll
    for (int n = 0; n < 4; ++n) s[n] = (f32x4){0.f, 0.f, 0.f, 0.f};
    __builtin_amdgcn_s_setprio(1);
    #pragma unroll
    for (int kf = 0; kf < 2; ++kf)
      #pragma unroll
      for (int nf = 0; nf < 4; ++nf) {
        int row = nf * 16 + lr;
        int g = (kf * 4 + lk) ^ (row & 7);
        bf16x8 bk = *(const bf16x8*)(&Ks[p][row * 64 + g * 8]);
        s[nf] = __builtin_amdgcn_mfma_f32_16x16x32_bf16(aq[kf], bk, s[nf], 0, 0, 0);
      }
    __builtin_amdgcn_s_setprio(0);
    #pragma unroll
    for (int nf = 0; nf < 4; ++nf)
      #pragma unroll
      for (int j = 0; j < 4; ++j) s[nf][j] *= 0.125f;

    if (kt == nt - 1) {
      #pragma unroll
      for (int nf = 0; nf < 4; ++nf) {
        int kl = nf * 16 + lr;
        #pragma unroll
        for (int j = 0; j < 4; ++j)
          if (kl > w * 16 + lk * 4 + j) s[nf][j] = -1e30f;
      }
    }

    float sc[4];
    #pragma unroll
    for (int j = 0; j < 4; ++j) {
      float pm = fmaxf(fmaxf(s[0][j], s[1][j]), fmaxf(s[2][j], s[3][j]));
      pm = fmaxf(pm, __shfl_xor(pm, 1, 64));
      pm = fmaxf(pm, __shfl_xor(pm, 2, 64));
      pm = fmaxf(pm, __shfl_xor(pm, 4, 64));
      pm = fmaxf(pm, __shfl_xor(pm, 8, 64));
      float mn = fmaxf(mrow[j], pm);
      sc[j] = __expf(mrow[j] - mn);
      mrow[j] = mn;
    }
    #pragma unroll
    for (int j = 0; j < 4; ++j) {
      float ls = 0.f;
      #pragma unroll
      for (int nf = 0; nf < 4; ++nf) {
        float p2 = __expf(s[nf][j] - mrow[j]);
        s[nf][j] = p2;
        ls += p2;
      }
      ls += __shfl_xor(ls, 1, 64);
      ls += __shfl_xor(ls, 2, 64);
      ls += __shfl_xor(ls, 4, 64);
      ls += __shfl_xor(ls, 8, 64);
      lrow[j] = lrow[j] * sc[j] + ls;
    }
    #pragma unroll
    for (int n = 0; n < 4; ++n)
      #pragma unroll
      for (int j = 0; j < 4; ++j) o[n][j] *= sc[j];

    short* pw = Ps[w];
    #pragma unroll
    for (int nf = 0; nf < 4; ++nf)
      #pragma unroll
      for (int j = 0; j < 4; ++j) {
        int ql = lk * 4 + j, k = nf * 16 + lr;
        pw[ql * 64 + (((k >> 3) ^ (ql & 7)) * 8) + (k & 7)] = f2bf(s[nf][j]);
      }
    bf16x8 pa[2];
    #pragma unroll
    for (int kf = 0; kf < 2; ++kf) {
      int g = (kf * 4 + lk) ^ (lr & 7);
      pa[kf] = *(const bf16x8*)(pw + lr * 64 + g * 8);
    }
    __builtin_amdgcn_s_setprio(1);
    #pragma unroll
    for (int kf = 0; kf < 2; ++kf)
      #pragma unroll
      for (int nf = 0; nf < 4; ++nf) {
        int d = nf * 16 + lr;
        int g = (kf * 4 + lk) ^ (d & 7);
        bf16x8 bv = *(const bf16x8*)(&Vts[p][d * 64 + g * 8]);
        o[nf] = __builtin_amdgcn_mfma_f32_16x16x32_bf16(pa[kf], bv, o[nf], 0, 0, 0);
      }
    __builtin_amdgcn_s_setprio(0);
    __syncthreads();   // drains next-tile stage + WAR for buf p
  }

  #pragma unroll
  for (int j = 0; j < 4; ++j) lrow[j] = 1.f / lrow[j];
  #pragma unroll
  for (int nf = 0; nf < 4; ++nf)
    #pragma unroll
    for (int j = 0; j < 4; ++j) {
      size_t oidx = ((size_t)(b * Tv + qb + w * 16 + lk * 4 + j)) * Dv + h * HDv + nf * 16 + lr;
      y[oidx] = __float2bfloat16(o[nf][j] * lrow[j]);
    }
}

extern "C" void kernel_launch(void* const* d_in, const int* in_sizes, int n_in,
                              void* d_out, int out_size, void* d_ws, size_t ws_size,
                              hipStream_t stream) {
  const int*   idx      = (const int*)  d_in[0];
  const float* wte      = (const float*)d_in[1];
  const float* wpe      = (const float*)d_in[2];
  const float* ln1_w    = (const float*)d_in[3];
  const float* ln1_b    = (const float*)d_in[4];
  const float* attn_w   = (const float*)d_in[5];
  const float* attn_b   = (const float*)d_in[6];
  const float* proj_w   = (const float*)d_in[7];
  const float* proj_b   = (const float*)d_in[8];
  const float* ln2_w    = (const float*)d_in[9];
  const float* ln2_b    = (const float*)d_in[10];
  const float* fc_w     = (const float*)d_in[11];
  const float* fc_b     = (const float*)d_in[12];
  const float* fcproj_w = (const float*)d_in[13];
  const float* fcproj_b = (const float*)d_in[14];
  const float* lnf_w    = (const float*)d_in[15];
  const float* lnf_b    = (const float*)d_in[16];
  const float* head_w   = (const float*)d_in[17];
  float* outp = (float*)d_out;

  char* w8 = (char*)d_ws;
  float*          x    = (float*)w8;                          // 2048*768 f32
  __hip_bfloat16* h    = (__hip_bfloat16*)(w8 + 6291456);     // 2048*768 bf16
  __hip_bfloat16* qkv  = (__hip_bfloat16*)(w8 + 9437184);     // 2048*2304 bf16
  __hip_bfloat16* m4   = qkv;                                 // 2048*3072 bf16 alias
  __hip_bfloat16* y    = (__hip_bfloat16*)(w8 + 22020096);    // 2048*768 bf16
  __hip_bfloat16* vt   = (__hip_bfloat16*)(w8 + 25165824);    // B*H*64*1024 bf16
  __hip_bfloat16* wbuf = (__hip_bfloat16*)(w8 + 28311552);    // weight staging

  __hip_bfloat16* wb_attn   = wbuf;
  __hip_bfloat16* wb_proj   = wb_attn + (size_t)768 * 2304;
  __hip_bfloat16* wb_fc     = wb_proj + (size_t)768 * 768;
  __hip_bfloat16* wb_fcproj = wb_fc   + (size_t)768 * 3072;

  embed_kernel<<<(MROWS * Dv / 4 + 255) / 256, 256, 0, stream>>>(idx, wte, wpe, x);

  for (int l = 0; l < Lv; ++l) {
    ln_tcast4_kernel<<<MROWS + 6912, 256, 0, stream>>>(
        x, ln1_w + (size_t)l * Dv, ln1_b + (size_t)l * Dv, h,
        attn_w   + (size_t)l * Dv * 3 * Dv,
        proj_w   + (size_t)l * Dv * Dv,
        fc_w     + (size_t)l * Dv * 4 * Dv,
        fcproj_w + (size_t)l * 4 * Dv * Dv,
        wb_attn, wb_proj, wb_fc, wb_fcproj);
    qkv_gemm_kernel<<<dim3(MROWS / 128, 3 * Dv / 128), 256, 0, stream>>>(
        h, wb_attn, attn_b + (size_t)l * 3 * Dv, qkv, vt, MROWS, 3 * Dv, Dv);
    attn_kernel<<<dim3(Tv / 64, Hv, Bv), 256, 0, stream>>>(qkv, vt, y);
    proj_gemm_kernel<<<dim3(MROWS / 64, Dv / 64), 256, 0, stream>>>(
        y, wb_proj, proj_b + (size_t)l * Dv, x, x, MROWS, Dv, Dv);
    ln_kernel<<<MROWS, 256, 0, stream>>>(x, ln2_w + (size_t)l * Dv, ln2_b + (size_t)l * Dv, h);
    fc_gemm_kernel<<<dim3(MROWS / 128, 4 * Dv / 128), 256, 0, stream>>>(
        h, wb_fc, fc_b + (size_t)l * 4 * Dv, m4, MROWS, 4 * Dv, Dv);
    fcproj_gemm_kernel<<<dim3(MROWS / 64, Dv / 64), 256, 0, stream>>>(
        m4, wb_fcproj, fcproj_b + (size_t)l * Dv, x, x, MROWS, Dv, 4 * Dv);
  }

  lnf_tcast_kernel<<<MROWS + 24000, 256, 0, stream>>>(
      x, lnf_w, lnf_b, h, head_w, wbuf);
  gemm256_kernel<<<dim3(MROWS / 256, Vv / 256), 512, 0, stream>>>(
      h, wbuf, outp, Vv, Dv);
}

// Round 12
// 1011.320 us; speedup vs baseline: 1.1512x; 1.0463x over previous
//
#include <hip/hip_runtime.h>
#include <hip/hip_bf16.h>
#include <math.h>

static constexpr int Bv = 2, Tv = 1024, Dv = 768, Hv = 12, Lv = 6, Vv = 32000, HDv = 64;
static constexpr int MROWS = Bv * Tv;   // 2048

typedef __attribute__((ext_vector_type(8))) short bf16x8;
typedef __attribute__((ext_vector_type(8))) short short8;
typedef __attribute__((ext_vector_type(4))) short short4v;
typedef __attribute__((ext_vector_type(4))) float f32x4;

typedef __attribute__((address_space(1))) const void gvoid;
typedef __attribute__((address_space(3))) void svoid;
__device__ __forceinline__ void gld16(const void* g, void* s) {
  __builtin_amdgcn_global_load_lds((gvoid*)g, (svoid*)s, 16, 0, 0);
}
__device__ __forceinline__ short f2bf(float v) {
  __hip_bfloat16 hb = __float2bfloat16(v);
  return *reinterpret_cast<short*>(&hb);
}
// bijective XCD-chunk remap (m204)
__device__ __forceinline__ int xcd_remap(int lin, int nwg) {
  int q = nwg >> 3, r = nwg & 7;
  int xcd = lin & 7, idx = lin >> 3;
  return (xcd < r ? xcd * (q + 1) : r * (q + 1) + (xcd - r) * q) + idx;
}

// ---------------- embedding ----------------
__global__ __launch_bounds__(256) void embed_kernel(const int* __restrict__ idx,
                                                    const float* __restrict__ wte,
                                                    const float* __restrict__ wpe,
                                                    float* __restrict__ x) {
  int i4 = blockIdx.x * 256 + threadIdx.x;
  int total = MROWS * Dv / 4;
  if (i4 >= total) return;
  int d4 = (i4 % (Dv / 4)) * 4;
  int bt = i4 / (Dv / 4);
  int t  = bt % Tv;
  int id = idx[bt];
  float4 a = *(const float4*)(wte + (size_t)id * Dv + d4);
  float4 p = *(const float4*)(wpe + (size_t)t  * Dv + d4);
  a.x += p.x; a.y += p.y; a.z += p.z; a.w += p.w;
  *(float4*)(x + (size_t)bt * Dv + d4) = a;
}

// ---------------- layernorm body: fp32 in -> bf16 out ----------------
__device__ __forceinline__ void ln_body(const float* __restrict__ x,
                                        const float* __restrict__ w,
                                        const float* __restrict__ b,
                                        __hip_bfloat16* __restrict__ out, int row) {
  __shared__ float red[8];
  const float* xr = x + (size_t)row * Dv;
  int tid = threadIdx.x;
  float v0 = xr[tid], v1 = xr[tid + 256], v2 = xr[tid + 512];
  int wid = tid >> 6, lane = tid & 63;

  float s = v0 + v1 + v2;
  #pragma unroll
  for (int off = 1; off < 64; off <<= 1) s += __shfl_xor(s, off, 64);
  if (lane == 0) red[wid] = s;
  __syncthreads();
  s = red[0] + red[1] + red[2] + red[3];
  float mu = s * (1.0f / Dv);

  float d0 = v0 - mu, d1 = v1 - mu, d2 = v2 - mu;
  float q = d0 * d0 + d1 * d1 + d2 * d2;
  #pragma unroll
  for (int off = 1; off < 64; off <<= 1) q += __shfl_xor(q, off, 64);
  if (lane == 0) red[4 + wid] = q;
  __syncthreads();
  q = red[4] + red[5] + red[6] + red[7];
  float rs = rsqrtf(q * (1.0f / Dv) + 1e-5f);

  __hip_bfloat16* orow = out + (size_t)row * Dv;
  orow[tid]       = __float2bfloat16(d0 * rs * w[tid]       + b[tid]);
  orow[tid + 256] = __float2bfloat16(d1 * rs * w[tid + 256] + b[tid + 256]);
  orow[tid + 512] = __float2bfloat16(d2 * rs * w[tid + 512] + b[tid + 512]);
}

__global__ __launch_bounds__(256) void ln_kernel(const float* __restrict__ x,
                                                 const float* __restrict__ w,
                                                 const float* __restrict__ b,
                                                 __hip_bfloat16* __restrict__ out) {
  ln_body(x, w, b, out, blockIdx.x);
}

// ---------------- transpose+cast body ----------------
__device__ __forceinline__ void tcast_body(const float* __restrict__ W,
                                           __hip_bfloat16* __restrict__ Wt,
                                           int K, int N, int k0, int n0) {
  __shared__ float tile[32][33];
  int tx = threadIdx.x & 31, ty = threadIdx.x >> 5;
  #pragma unroll
  for (int r = 0; r < 32; r += 8)
    tile[ty + r][tx] = W[(size_t)(k0 + ty + r) * N + n0 + tx];
  __syncthreads();
  #pragma unroll
  for (int r = 0; r < 32; r += 8)
    Wt[(size_t)(n0 + ty + r) * K + k0 + tx] = __float2bfloat16(tile[tx][ty + r]);
}

// ---------------- fused ln1 + 4-weight tcast (per layer) -------------------
__global__ __launch_bounds__(256) void ln_tcast4_kernel(const float* __restrict__ x,
                                                        const float* __restrict__ lw,
                                                        const float* __restrict__ lb,
                                                        __hip_bfloat16* __restrict__ h,
                                                        const float* __restrict__ s0,
                                                        const float* __restrict__ s1,
                                                        const float* __restrict__ s2,
                                                        const float* __restrict__ s3,
                                                        __hip_bfloat16* __restrict__ d0,
                                                        __hip_bfloat16* __restrict__ d1,
                                                        __hip_bfloat16* __restrict__ d2,
                                                        __hip_bfloat16* __restrict__ d3) {
  int blk = blockIdx.x;
  if (blk < MROWS) { ln_body(x, lw, lb, h, blk); return; }
  int lin = blk - MROWS;
  const float* W; __hip_bfloat16* Wt; int K, N, loc;
  if (lin < 1728)      { W = s0; Wt = d0; K = 768;  N = 2304; loc = lin; }
  else if (lin < 2304) { W = s1; Wt = d1; K = 768;  N = 768;  loc = lin - 1728; }
  else if (lin < 4608) { W = s2; Wt = d2; K = 768;  N = 3072; loc = lin - 2304; }
  else                 { W = s3; Wt = d3; K = 3072; N = 768;  loc = lin - 4608; }
  int nb = N / 32;
  tcast_body(W, Wt, K, N, (loc / nb) * 32, (loc % nb) * 32);
}

// ---------------- fused lnf + head tcast -----------------------------------
__global__ __launch_bounds__(256) void lnf_tcast_kernel(const float* __restrict__ x,
                                                        const float* __restrict__ lw,
                                                        const float* __restrict__ lb,
                                                        __hip_bfloat16* __restrict__ h,
                                                        const float* __restrict__ head_w,
                                                        __hip_bfloat16* __restrict__ wb) {
  int blk = blockIdx.x;
  if (blk < MROWS) { ln_body(x, lw, lb, h, blk); return; }
  int loc = blk - MROWS;                 // 0..23999
  int nb = Vv / 32;                      // 1000
  tcast_body(head_w, wb, Dv, Vv, (loc / nb) * 32, (loc % nb) * 32);
}

// ---------------- 64x64 MFMA GEMM body (BK=64, swizzled, 2-phase dbuf) -----
// Templated epilogue (mirrors the proven gemm128 epilogue): GELU, bf16 out,
// V-transpose scatter. High grid count (M/64 x N/64) -> 4-6 blocks/CU, which
// hides staging latency that the 128^2 grids (1.1-1.5 blocks/CU) could not.
template <bool GELU, bool OBF, bool VT>
__device__ __forceinline__ void gemm64_body(const __hip_bfloat16* __restrict__ A,
                                            const __hip_bfloat16* __restrict__ Wt,
                                            const float* __restrict__ bias,
                                            const float* __restrict__ resid,
                                            void* __restrict__ outv,
                                            __hip_bfloat16* __restrict__ vt,
                                            int M, int N, int K) {
  __shared__ short As[2][4096];
  __shared__ short Bs[2][4096];
  int nwg = gridDim.x * gridDim.y;
  int wgid = xcd_remap(blockIdx.y * gridDim.x + blockIdx.x, nwg);
  int m0 = (wgid % gridDim.x) * 64, n0 = (wgid / gridDim.x) * 64;

  int tid = threadIdx.x;
  int w = tid >> 6, lane = tid & 63;
  int wr = w >> 1, wc = w & 1;
  int lr = lane & 15, lk = lane >> 4;
  int rsub = lane >> 3, go = lane & 7;

  f32x4 acc[2][2];
  #pragma unroll
  for (int m = 0; m < 2; ++m)
    #pragma unroll
    for (int n = 0; n < 2; ++n) acc[m][n] = (f32x4){0.f, 0.f, 0.f, 0.f};

  auto stg = [&](int k0, int p) {
    #pragma unroll
    for (int e = 0; e < 2; ++e) {
      int row = w * 16 + e * 8 + rsub;
      int gs = (go ^ rsub) * 8;
      gld16(A  + (size_t)(m0 + row) * K + k0 + gs, &As[p][w * 1024 + e * 512]);
      gld16(Wt + (size_t)(n0 + row) * K + k0 + gs, &Bs[p][w * 1024 + e * 512]);
    }
  };

  stg(0, 0);
  __syncthreads();
  int NK = K >> 6;
  for (int kt = 0; kt < NK; ++kt) {
    int p = kt & 1;
    if (kt + 1 < NK) stg((kt + 1) << 6, p ^ 1);
    #pragma unroll
    for (int kf = 0; kf < 2; ++kf) {
      bf16x8 af[2], bf[2];
      #pragma unroll
      for (int m = 0; m < 2; ++m) {
        int row = wr * 32 + m * 16 + lr;
        af[m] = *(const bf16x8*)(&As[p][row * 64 + (((kf * 4 + lk) ^ (row & 7)) * 8)]);
      }
      #pragma unroll
      for (int n = 0; n < 2; ++n) {
        int row = wc * 32 + n * 16 + lr;
        bf[n] = *(const bf16x8*)(&Bs[p][row * 64 + (((kf * 4 + lk) ^ (row & 7)) * 8)]);
      }
      #pragma unroll
      for (int m = 0; m < 2; ++m)
        #pragma unroll
        for (int n = 0; n < 2; ++n)
          acc[m][n] = __builtin_amdgcn_mfma_f32_16x16x32_bf16(af[m], bf[n], acc[m][n], 0, 0, 0);
    }
    __syncthreads();
  }

  int row0 = m0 + wr * 32, col0 = n0 + wc * 32;
  float* outf = (float*)outv;
  __hip_bfloat16* outb = (__hip_bfloat16*)outv;
  #pragma unroll
  for (int n = 0; n < 2; ++n) {
    int col = col0 + n * 16 + lr;
    float bv = bias ? bias[col] : 0.f;
    #pragma unroll
    for (int m = 0; m < 2; ++m) {
      int rbase = row0 + m * 16 + lk * 4;
      float r4[4];
      #pragma unroll
      for (int j = 0; j < 4; ++j) {
        float v = acc[m][n][j] + bv;
        if (GELU) v = 0.5f * v * (1.0f + erff(v * 0.70710678118f));
        size_t o = (size_t)(rbase + j) * N + col;
        if (resid) v += resid[o];
        r4[j] = v;
        if (OBF) outb[o] = __float2bfloat16(v);
        else     outf[o] = v;
      }
      if (VT && col >= 2 * Dv) {
        int hh = (col - 2 * Dv) >> 6, dd = (col - 2 * Dv) & 63;
        int bb = rbase >> 10, t0 = rbase & 1023;
        short4v pk = {f2bf(r4[0]), f2bf(r4[1]), f2bf(r4[2]), f2bf(r4[3])};
        *(short4v*)(vt + (((size_t)(bb * Hv + hh) * HDv + dd) << 10) + t0) = pk;
      }
    }
  }
}

__global__ __launch_bounds__(256) void qkv_gemm_kernel(const __hip_bfloat16* A,
                                                       const __hip_bfloat16* Wt,
                                                       const float* bias,
                                                       void* outv, __hip_bfloat16* vt,
                                                       int M, int N, int K) {
  gemm64_body<false, true, true>(A, Wt, bias, nullptr, outv, vt, M, N, K);
}
__global__ __launch_bounds__(256) void fc_gemm_kernel(const __hip_bfloat16* A,
                                                      const __hip_bfloat16* Wt,
                                                      const float* bias,
                                                      void* outv, int M, int N, int K) {
  gemm64_body<true, true, false>(A, Wt, bias, nullptr, outv, nullptr, M, N, K);
}
__global__ __launch_bounds__(256) void proj_gemm_kernel(const __hip_bfloat16* A,
                                                        const __hip_bfloat16* Wt,
                                                        const float* bias,
                                                        const float* resid, float* out,
                                                        int M, int N, int K) {
  gemm64_body<false, false, false>(A, Wt, bias, resid, out, nullptr, M, N, K);
}
__global__ __launch_bounds__(256) void fcproj_gemm_kernel(const __hip_bfloat16* A,
                                                          const __hip_bfloat16* Wt,
                                                          const float* bias,
                                                          const float* resid, float* out,
                                                          int M, int N, int K) {
  gemm64_body<false, false, false>(A, Wt, bias, resid, out, nullptr, M, N, K);
}

// ---------------- 256x256 4-phase counted-vmcnt GEMM (head) ---------------
// Round-6/8 proven schedule: prologue vmcnt(4)+barrier, loop vmcnt(4),
// phantom stages keep the ledger uniform through the final tile. Invariant:
// each half's per-wave retire happens >=1 phase (w/ barrier) before first read.
__global__ __launch_bounds__(512, 2) void gemm256_kernel(const __hip_bfloat16* __restrict__ A,
                                                         const __hip_bfloat16* __restrict__ Wt,
                                                         float* __restrict__ out,
                                                         int N, int K) {
  __shared__ short lds[65536];   // 128 KB
  int nwg = gridDim.x * gridDim.y;
  int wgid = xcd_remap(blockIdx.y * gridDim.x + blockIdx.x, nwg);
  int m0 = (wgid % gridDim.x) * 256, n0 = (wgid / gridDim.x) * 256;

  int tid = threadIdx.x;
  int w = tid >> 6, lane = tid & 63;
  int wr = w >> 2, wc = w & 3;          // 2 x 4 waves
  int lr = lane & 15, lk = lane >> 4;

  f32x4 acc[8][4];
  #pragma unroll
  for (int m = 0; m < 8; ++m)
    #pragma unroll
    for (int n = 0; n < 4; ++n) acc[m][n] = (f32x4){0.f, 0.f, 0.f, 0.f};

  int NT = K >> 6;

  auto stage = [&](int tau, int h) {
    int tsrc = tau < NT ? tau : NT - 1;       // phantom: re-read last tile
    const __hip_bfloat16* mat;
    size_t rb; int lofs;
    if (h == 0)      { mat = A;  rb = (size_t)m0;       lofs = 0; }
    else if (h == 1) { mat = Wt; rb = (size_t)n0;       lofs = 16384; }
    else if (h == 2) { mat = Wt; rb = (size_t)n0 + 128; lofs = 24576; }
    else             { mat = A;  rb = (size_t)m0 + 128; lofs = 8192; }
    short* lb = lds + (tau & 1) * 32768 + lofs;   // parity of REQUESTED tile
    #pragma unroll
    for (int e = 0; e < 2; ++e) {
      int idx = e * 512 + tid;
      int r = idx >> 3, g = idx & 7;
      gld16(mat + (rb + r) * (size_t)K + tsrc * 64 + ((g ^ (r & 7)) * 8), lb + idx * 8);
    }
  };

  stage(0, 0); stage(0, 1); stage(0, 2); stage(0, 3);
  asm volatile("s_waitcnt vmcnt(4)" ::: "memory");
  asm volatile("s_barrier" ::: "memory");

  for (int tau = 0; tau < NT; ++tau) {
    const short* bufA = lds + (tau & 1) * 32768;
    const short* bufB = bufA + 16384;
    #pragma unroll
    for (int q = 0; q < 4; ++q) {
      stage(tau + 1, q);
      asm volatile("s_waitcnt vmcnt(4)" ::: "memory");
      int qm = q >> 1, qn = q & 1;
      const short* ab = bufA + qm * 8192;
      const short* bb = bufB + qn * 8192;
      bf16x8 af[4][2], bf[2][2];
      #pragma unroll
      for (int mi = 0; mi < 4; ++mi) {
        int ra = wr * 64 + mi * 16 + lr;
        #pragma unroll
        for (int kf = 0; kf < 2; ++kf)
          af[mi][kf] = *(const bf16x8*)(ab + ra * 64 + (((kf * 4 + lk) ^ (ra & 7)) * 8));
      }
      #pragma unroll
      for (int ni = 0; ni < 2; ++ni) {
        int rb2 = wc * 32 + ni * 16 + lr;
        #pragma unroll
        for (int kf = 0; kf < 2; ++kf)
          bf[ni][kf] = *(const bf16x8*)(bb + rb2 * 64 + (((kf * 4 + lk) ^ (rb2 & 7)) * 8));
      }
      asm volatile("s_barrier" ::: "memory");
      __builtin_amdgcn_s_setprio(1);
      #pragma unroll
      for (int mi = 0; mi < 4; ++mi)
        #pragma unroll
        for (int ni = 0; ni < 2; ++ni)
          #pragma unroll
          for (int kf = 0; kf < 2; ++kf)
            acc[qm * 4 + mi][qn * 2 + ni] = __builtin_amdgcn_mfma_f32_16x16x32_bf16(
                af[mi][kf], bf[ni][kf], acc[qm * 4 + mi][qn * 2 + ni], 0, 0, 0);
      __builtin_amdgcn_s_setprio(0);
      asm volatile("s_barrier" ::: "memory");
    }
  }

  #pragma unroll
  for (int gm = 0; gm < 8; ++gm) {
    int row = m0 + (gm >> 2) * 128 + wr * 64 + (gm & 3) * 16 + lk * 4;
    #pragma unroll
    for (int gn = 0; gn < 4; ++gn) {
      int col = n0 + (gn >> 1) * 128 + wc * 32 + (gn & 1) * 16 + lr;
      #pragma unroll
      for (int j = 0; j < 4; ++j)
        out[(size_t)(row + j) * N + col] = acc[gm][gn][j];
    }
  }
}

// ---------------- MFMA flash attention (K/V dbuf + setprio, LPT order) -----
// grid: 384 blocks 1D. rank r = lin/24 -> qb = (15-r)*64 (largest first, LPT);
// (b,h) = lin%24. Inner loop identical to the round-8..11 proven kernel.
__global__ __launch_bounds__(256) void attn_kernel(const __hip_bfloat16* __restrict__ qkv,
                                                   const __hip_bfloat16* __restrict__ vt,
                                                   __hip_bfloat16* __restrict__ y) {
  __shared__ short Ks[2][4096];
  __shared__ short Vts[2][4096];
  __shared__ short Ps[4][1024];
  int lin = blockIdx.x;
  int bh = lin % 24;
  int b = bh / Hv, h = bh % Hv;
  int qb = (Tv / 64 - 1 - lin / 24) * 64;
  int tid = threadIdx.x;
  int w = tid >> 6, l = tid & 63;
  int lr = l & 15, lk = l >> 4;

  bf16x8 aq[2];
  {
    const __hip_bfloat16* qp = qkv + ((size_t)(b * Tv + qb + w * 16 + lr)) * 3 * Dv + h * HDv + lk * 8;
    aq[0] = *(const bf16x8*)qp;
    aq[1] = *(const bf16x8*)(qp + 32);
  }

  f32x4 o[4];
  #pragma unroll
  for (int n = 0; n < 4; ++n) o[n] = (f32x4){0.f, 0.f, 0.f, 0.f};
  float mrow[4] = {-1e30f, -1e30f, -1e30f, -1e30f};
  float lrow[4] = {0.f, 0.f, 0.f, 0.f};

  int r8 = l >> 3, c8 = l & 7;
  int nt = qb / 64 + 1;

  auto stageKV = [&](int kt2, int p) {
    int kbase = kt2 * 64;
    #pragma unroll
    for (int e = 0; e < 2; ++e) {
      int r0 = w * 16 + e * 8;
      int rK = r0 + r8;
      int csK = c8 ^ (rK & 7);
      gld16(qkv + ((size_t)(b * Tv + kbase + rK)) * 3 * Dv + Dv + h * HDv + csK * 8,
            &Ks[p][r0 * 64]);
      gld16(vt + ((size_t)((b * Hv + h) * HDv + rK)) * Tv + kbase + csK * 8,
            &Vts[p][r0 * 64]);
    }
  };

  stageKV(0, 0);
  __syncthreads();

  for (int kt = 0; kt < nt; ++kt) {
    int p = kt & 1;
    if (kt + 1 < nt) stageKV(kt + 1, p ^ 1);

    f32x4 s[4];
    #pragma unroll
    for (int n = 0; n < 4; ++n) s[n] = (f32x4){0.f, 0.f, 0.f, 0.f};
    __builtin_amdgcn_s_setprio(1);
    #pragma unroll
    for (int kf = 0; kf < 2; ++kf)
      #pragma unroll
      for (int nf = 0; nf < 4; ++nf) {
        int row = nf * 16 + lr;
        int g = (kf * 4 + lk) ^ (row & 7);
        bf16x8 bk = *(const bf16x8*)(&Ks[p][row * 64 + g * 8]);
        s[nf] = __builtin_amdgcn_mfma_f32_16x16x32_bf16(aq[kf], bk, s[nf], 0, 0, 0);
      }
    __builtin_amdgcn_s_setprio(0);
    #pragma unroll
    for (int nf = 0; nf < 4; ++nf)
      #pragma unroll
      for (int j = 0; j < 4; ++j) s[nf][j] *= 0.125f;

    if (kt == nt - 1) {
      #pragma unroll
      for (int nf = 0; nf < 4; ++nf) {
        int kl = nf * 16 + lr;
        #pragma unroll
        for (int j = 0; j < 4; ++j)
          if (kl > w * 16 + lk * 4 + j) s[nf][j] = -1e30f;
      }
    }

    float sc[4];
    #pragma unroll
    for (int j = 0; j < 4; ++j) {
      float pm = fmaxf(fmaxf(s[0][j], s[1][j]), fmaxf(s[2][j], s[3][j]));
      pm = fmaxf(pm, __shfl_xor(pm, 1, 64));
      pm = fmaxf(pm, __shfl_xor(pm, 2, 64));
      pm = fmaxf(pm, __shfl_xor(pm, 4, 64));
      pm = fmaxf(pm, __shfl_xor(pm, 8, 64));
      float mn = fmaxf(mrow[j], pm);
      sc[j] = __expf(mrow[j] - mn);
      mrow[j] = mn;
    }
    #pragma unroll
    for (int j = 0; j < 4; ++j) {
      float ls = 0.f;
      #pragma unroll
      for (int nf = 0; nf < 4; ++nf) {
        float p2 = __expf(s[nf][j] - mrow[j]);
        s[nf][j] = p2;
        ls += p2;
      }
      ls += __shfl_xor(ls, 1, 64);
      ls += __shfl_xor(ls, 2, 64);
      ls += __shfl_xor(ls, 4, 64);
      ls += __shfl_xor(ls, 8, 64);
      lrow[j] = lrow[j] * sc[j] + ls;
    }
    #pragma unroll
    for (int n = 0; n < 4; ++n)
      #pragma unroll
      for (int j = 0; j < 4; ++j) o[n][j] *= sc[j];

    short* pw = Ps[w];
    #pragma unroll
    for (int nf = 0; nf < 4; ++nf)
      #pragma unroll
      for (int j = 0; j < 4; ++j) {
        int ql = lk * 4 + j, k = nf * 16 + lr;
        pw[ql * 64 + (((k >> 3) ^ (ql & 7)) * 8) + (k & 7)] = f2bf(s[nf][j]);
      }
    bf16x8 pa[2];
    #pragma unroll
    for (int kf = 0; kf < 2; ++kf) {
      int g = (kf * 4 + lk) ^ (lr & 7);
      pa[kf] = *(const bf16x8*)(pw + lr * 64 + g * 8);
    }
    __builtin_amdgcn_s_setprio(1);
    #pragma unroll
    for (int kf = 0; kf < 2; ++kf)
      #pragma unroll
      for (int nf = 0; nf < 4; ++nf) {
        int d = nf * 16 + lr;
        int g = (kf * 4 + lk) ^ (d & 7);
        bf16x8 bv = *(const bf16x8*)(&Vts[p][d * 64 + g * 8]);
        o[nf] = __builtin_amdgcn_mfma_f32_16x16x32_bf16(pa[kf], bv, o[nf], 0, 0, 0);
      }
    __builtin_amdgcn_s_setprio(0);
    __syncthreads();   // drains next-tile stage + WAR for buf p
  }

  #pragma unroll
  for (int j = 0; j < 4; ++j) lrow[j] = 1.f / lrow[j];
  #pragma unroll
  for (int nf = 0; nf < 4; ++nf)
    #pragma unroll
    for (int j = 0; j < 4; ++j) {
      size_t oidx = ((size_t)(b * Tv + qb + w * 16 + lk * 4 + j)) * Dv + h * HDv + nf * 16 + lr;
      y[oidx] = __float2bfloat16(o[nf][j] * lrow[j]);
    }
}

extern "C" void kernel_launch(void* const* d_in, const int* in_sizes, int n_in,
                              void* d_out, int out_size, void* d_ws, size_t ws_size,
                              hipStream_t stream) {
  const int*   idx      = (const int*)  d_in[0];
  const float* wte      = (const float*)d_in[1];
  const float* wpe      = (const float*)d_in[2];
  const float* ln1_w    = (const float*)d_in[3];
  const float* ln1_b    = (const float*)d_in[4];
  const float* attn_w   = (const float*)d_in[5];
  const float* attn_b   = (const float*)d_in[6];
  const float* proj_w   = (const float*)d_in[7];
  const float* proj_b   = (const float*)d_in[8];
  const float* ln2_w    = (const float*)d_in[9];
  const float* ln2_b    = (const float*)d_in[10];
  const float* fc_w     = (const float*)d_in[11];
  const float* fc_b     = (const float*)d_in[12];
  const float* fcproj_w = (const float*)d_in[13];
  const float* fcproj_b = (const float*)d_in[14];
  const float* lnf_w    = (const float*)d_in[15];
  const float* lnf_b    = (const float*)d_in[16];
  const float* head_w   = (const float*)d_in[17];
  float* outp = (float*)d_out;

  char* w8 = (char*)d_ws;
  float*          x    = (float*)w8;                          // 2048*768 f32
  __hip_bfloat16* h    = (__hip_bfloat16*)(w8 + 6291456);     // 2048*768 bf16
  __hip_bfloat16* qkv  = (__hip_bfloat16*)(w8 + 9437184);     // 2048*2304 bf16
  __hip_bfloat16* m4   = qkv;                                 // 2048*3072 bf16 alias
  __hip_bfloat16* y    = (__hip_bfloat16*)(w8 + 22020096);    // 2048*768 bf16
  __hip_bfloat16* vt   = (__hip_bfloat16*)(w8 + 25165824);    // B*H*64*1024 bf16
  __hip_bfloat16* wbuf = (__hip_bfloat16*)(w8 + 28311552);    // weight staging

  __hip_bfloat16* wb_attn   = wbuf;
  __hip_bfloat16* wb_proj   = wb_attn + (size_t)768 * 2304;
  __hip_bfloat16* wb_fc     = wb_proj + (size_t)768 * 768;
  __hip_bfloat16* wb_fcproj = wb_fc   + (size_t)768 * 3072;

  embed_kernel<<<(MROWS * Dv / 4 + 255) / 256, 256, 0, stream>>>(idx, wte, wpe, x);

  for (int l = 0; l < Lv; ++l) {
    ln_tcast4_kernel<<<MROWS + 6912, 256, 0, stream>>>(
        x, ln1_w + (size_t)l * Dv, ln1_b + (size_t)l * Dv, h,
        attn_w   + (size_t)l * Dv * 3 * Dv,
        proj_w   + (size_t)l * Dv * Dv,
        fc_w     + (size_t)l * Dv * 4 * Dv,
        fcproj_w + (size_t)l * 4 * Dv * Dv,
        wb_attn, wb_proj, wb_fc, wb_fcproj);
    qkv_gemm_kernel<<<dim3(MROWS / 64, 3 * Dv / 64), 256, 0, stream>>>(
        h, wb_attn, attn_b + (size_t)l * 3 * Dv, qkv, vt, MROWS, 3 * Dv, Dv);
    attn_kernel<<<(Tv / 64) * Hv * Bv, 256, 0, stream>>>(qkv, vt, y);
    proj_gemm_kernel<<<dim3(MROWS / 64, Dv / 64), 256, 0, stream>>>(
        y, wb_proj, proj_b + (size_t)l * Dv, x, x, MROWS, Dv, Dv);
    ln_kernel<<<MROWS, 256, 0, stream>>>(x, ln2_w + (size_t)l * Dv, ln2_b + (size_t)l * Dv, h);
    fc_gemm_kernel<<<dim3(MROWS / 64, 4 * Dv / 64), 256, 0, stream>>>(
        h, wb_fc, fc_b + (size_t)l * 4 * Dv, m4, MROWS, 4 * Dv, Dv);
    fcproj_gemm_kernel<<<dim3(MROWS / 64, Dv / 64), 256, 0, stream>>>(
        m4, wb_fcproj, fcproj_b + (size_t)l * Dv, x, x, MROWS, Dv, 4 * Dv);
  }

  lnf_tcast_kernel<<<MROWS + 24000, 256, 0, stream>>>(
      x, lnf_w, lnf_b, h, head_w, wbuf);
  gemm256_kernel<<<dim3(MROWS / 256, Vv / 256), 512, 0, stream>>>(
      h, wbuf, outp, Vv, Dv);
}

// Round 13
// 987.804 us; speedup vs baseline: 1.1786x; 1.0238x over previous
//
#include <hip/hip_runtime.h>
#include <hip/hip_bf16.h>
#include <math.h>

static constexpr int Bv = 2, Tv = 1024, Dv = 768, Hv = 12, Lv = 6, Vv = 32000, HDv = 64;
static constexpr int MROWS = Bv * Tv;   // 2048

typedef __attribute__((ext_vector_type(8))) short bf16x8;
typedef __attribute__((ext_vector_type(8))) short short8;
typedef __attribute__((ext_vector_type(4))) short short4v;
typedef __attribute__((ext_vector_type(4))) float f32x4;

typedef __attribute__((address_space(1))) const void gvoid;
typedef __attribute__((address_space(3))) void svoid;
__device__ __forceinline__ void gld16(const void* g, void* s) {
  __builtin_amdgcn_global_load_lds((gvoid*)g, (svoid*)s, 16, 0, 0);
}
__device__ __forceinline__ short f2bf(float v) {
  __hip_bfloat16 hb = __float2bfloat16(v);
  return *reinterpret_cast<short*>(&hb);
}
// bijective XCD-chunk remap (m204)
__device__ __forceinline__ int xcd_remap(int lin, int nwg) {
  int q = nwg >> 3, r = nwg & 7;
  int xcd = lin & 7, idx = lin >> 3;
  return (xcd < r ? xcd * (q + 1) : r * (q + 1) + (xcd - r) * q) + idx;
}

// ---------------- embedding ----------------
__global__ __launch_bounds__(256) void embed_kernel(const int* __restrict__ idx,
                                                    const float* __restrict__ wte,
                                                    const float* __restrict__ wpe,
                                                    float* __restrict__ x) {
  int i4 = blockIdx.x * 256 + threadIdx.x;
  int total = MROWS * Dv / 4;
  if (i4 >= total) return;
  int d4 = (i4 % (Dv / 4)) * 4;
  int bt = i4 / (Dv / 4);
  int t  = bt % Tv;
  int id = idx[bt];
  float4 a = *(const float4*)(wte + (size_t)id * Dv + d4);
  float4 p = *(const float4*)(wpe + (size_t)t  * Dv + d4);
  a.x += p.x; a.y += p.y; a.z += p.z; a.w += p.w;
  *(float4*)(x + (size_t)bt * Dv + d4) = a;
}

// ---------------- layernorm body: fp32 in -> bf16 out ----------------
__device__ __forceinline__ void ln_body(const float* __restrict__ x,
                                        const float* __restrict__ w,
                                        const float* __restrict__ b,
                                        __hip_bfloat16* __restrict__ out, int row) {
  __shared__ float red[8];
  const float* xr = x + (size_t)row * Dv;
  int tid = threadIdx.x;
  float v0 = xr[tid], v1 = xr[tid + 256], v2 = xr[tid + 512];
  int wid = tid >> 6, lane = tid & 63;

  float s = v0 + v1 + v2;
  #pragma unroll
  for (int off = 1; off < 64; off <<= 1) s += __shfl_xor(s, off, 64);
  if (lane == 0) red[wid] = s;
  __syncthreads();
  s = red[0] + red[1] + red[2] + red[3];
  float mu = s * (1.0f / Dv);

  float d0 = v0 - mu, d1 = v1 - mu, d2 = v2 - mu;
  float q = d0 * d0 + d1 * d1 + d2 * d2;
  #pragma unroll
  for (int off = 1; off < 64; off <<= 1) q += __shfl_xor(q, off, 64);
  if (lane == 0) red[4 + wid] = q;
  __syncthreads();
  q = red[4] + red[5] + red[6] + red[7];
  float rs = rsqrtf(q * (1.0f / Dv) + 1e-5f);

  __hip_bfloat16* orow = out + (size_t)row * Dv;
  orow[tid]       = __float2bfloat16(d0 * rs * w[tid]       + b[tid]);
  orow[tid + 256] = __float2bfloat16(d1 * rs * w[tid + 256] + b[tid + 256]);
  orow[tid + 512] = __float2bfloat16(d2 * rs * w[tid + 512] + b[tid + 512]);
}

__global__ __launch_bounds__(256) void ln_kernel(const float* __restrict__ x,
                                                 const float* __restrict__ w,
                                                 const float* __restrict__ b,
                                                 __hip_bfloat16* __restrict__ out) {
  ln_body(x, w, b, out, blockIdx.x);
}

// ---------------- transpose+cast body ----------------
__device__ __forceinline__ void tcast_body(const float* __restrict__ W,
                                           __hip_bfloat16* __restrict__ Wt,
                                           int K, int N, int k0, int n0) {
  __shared__ float tile[32][33];
  int tx = threadIdx.x & 31, ty = threadIdx.x >> 5;
  #pragma unroll
  for (int r = 0; r < 32; r += 8)
    tile[ty + r][tx] = W[(size_t)(k0 + ty + r) * N + n0 + tx];
  __syncthreads();
  #pragma unroll
  for (int r = 0; r < 32; r += 8)
    Wt[(size_t)(n0 + ty + r) * K + k0 + tx] = __float2bfloat16(tile[tx][ty + r]);
}

// ---------------- fused ln1 + 4-weight tcast (per layer) -------------------
__global__ __launch_bounds__(256) void ln_tcast4_kernel(const float* __restrict__ x,
                                                        const float* __restrict__ lw,
                                                        const float* __restrict__ lb,
                                                        __hip_bfloat16* __restrict__ h,
                                                        const float* __restrict__ s0,
                                                        const float* __restrict__ s1,
                                                        const float* __restrict__ s2,
                                                        const float* __restrict__ s3,
                                                        __hip_bfloat16* __restrict__ d0,
                                                        __hip_bfloat16* __restrict__ d1,
                                                        __hip_bfloat16* __restrict__ d2,
                                                        __hip_bfloat16* __restrict__ d3) {
  int blk = blockIdx.x;
  if (blk < MROWS) { ln_body(x, lw, lb, h, blk); return; }
  int lin = blk - MROWS;
  const float* W; __hip_bfloat16* Wt; int K, N, loc;
  if (lin < 1728)      { W = s0; Wt = d0; K = 768;  N = 2304; loc = lin; }
  else if (lin < 2304) { W = s1; Wt = d1; K = 768;  N = 768;  loc = lin - 1728; }
  else if (lin < 4608) { W = s2; Wt = d2; K = 768;  N = 3072; loc = lin - 2304; }
  else                 { W = s3; Wt = d3; K = 3072; N = 768;  loc = lin - 4608; }
  int nb = N / 32;
  tcast_body(W, Wt, K, N, (loc / nb) * 32, (loc % nb) * 32);
}

// ---------------- fused lnf + head tcast -----------------------------------
__global__ __launch_bounds__(256) void lnf_tcast_kernel(const float* __restrict__ x,
                                                        const float* __restrict__ lw,
                                                        const float* __restrict__ lb,
                                                        __hip_bfloat16* __restrict__ h,
                                                        const float* __restrict__ head_w,
                                                        __hip_bfloat16* __restrict__ wb) {
  int blk = blockIdx.x;
  if (blk < MROWS) { ln_body(x, lw, lb, h, blk); return; }
  int loc = blk - MROWS;                 // 0..23999
  int nb = Vv / 32;                      // 1000
  tcast_body(head_w, wb, Dv, Vv, (loc / nb) * 32, (loc % nb) * 32);
}

// ---------------- 64x64 MFMA GEMM body (BK=64, swizzled, 2-phase dbuf) -----
template <bool GELU, bool OBF, bool VT>
__device__ __forceinline__ void gemm64_body(const __hip_bfloat16* __restrict__ A,
                                            const __hip_bfloat16* __restrict__ Wt,
                                            const float* __restrict__ bias,
                                            const float* __restrict__ resid,
                                            void* __restrict__ outv,
                                            __hip_bfloat16* __restrict__ vt,
                                            int M, int N, int K) {
  __shared__ short As[2][4096];
  __shared__ short Bs[2][4096];
  int nwg = gridDim.x * gridDim.y;
  int wgid = xcd_remap(blockIdx.y * gridDim.x + blockIdx.x, nwg);
  int m0 = (wgid % gridDim.x) * 64, n0 = (wgid / gridDim.x) * 64;

  int tid = threadIdx.x;
  int w = tid >> 6, lane = tid & 63;
  int wr = w >> 1, wc = w & 1;
  int lr = lane & 15, lk = lane >> 4;
  int rsub = lane >> 3, go = lane & 7;

  f32x4 acc[2][2];
  #pragma unroll
  for (int m = 0; m < 2; ++m)
    #pragma unroll
    for (int n = 0; n < 2; ++n) acc[m][n] = (f32x4){0.f, 0.f, 0.f, 0.f};

  auto stg = [&](int k0, int p) {
    #pragma unroll
    for (int e = 0; e < 2; ++e) {
      int row = w * 16 + e * 8 + rsub;
      int gs = (go ^ rsub) * 8;
      gld16(A  + (size_t)(m0 + row) * K + k0 + gs, &As[p][w * 1024 + e * 512]);
      gld16(Wt + (size_t)(n0 + row) * K + k0 + gs, &Bs[p][w * 1024 + e * 512]);
    }
  };

  stg(0, 0);
  __syncthreads();
  int NK = K >> 6;
  for (int kt = 0; kt < NK; ++kt) {
    int p = kt & 1;
    if (kt + 1 < NK) stg((kt + 1) << 6, p ^ 1);
    #pragma unroll
    for (int kf = 0; kf < 2; ++kf) {
      bf16x8 af[2], bf[2];
      #pragma unroll
      for (int m = 0; m < 2; ++m) {
        int row = wr * 32 + m * 16 + lr;
        af[m] = *(const bf16x8*)(&As[p][row * 64 + (((kf * 4 + lk) ^ (row & 7)) * 8)]);
      }
      #pragma unroll
      for (int n = 0; n < 2; ++n) {
        int row = wc * 32 + n * 16 + lr;
        bf[n] = *(const bf16x8*)(&Bs[p][row * 64 + (((kf * 4 + lk) ^ (row & 7)) * 8)]);
      }
      #pragma unroll
      for (int m = 0; m < 2; ++m)
        #pragma unroll
        for (int n = 0; n < 2; ++n)
          acc[m][n] = __builtin_amdgcn_mfma_f32_16x16x32_bf16(af[m], bf[n], acc[m][n], 0, 0, 0);
    }
    __syncthreads();
  }

  int row0 = m0 + wr * 32, col0 = n0 + wc * 32;
  float* outf = (float*)outv;
  __hip_bfloat16* outb = (__hip_bfloat16*)outv;
  #pragma unroll
  for (int n = 0; n < 2; ++n) {
    int col = col0 + n * 16 + lr;
    float bv = bias ? bias[col] : 0.f;
    #pragma unroll
    for (int m = 0; m < 2; ++m) {
      int rbase = row0 + m * 16 + lk * 4;
      float r4[4];
      #pragma unroll
      for (int j = 0; j < 4; ++j) {
        float v = acc[m][n][j] + bv;
        if (GELU) v = 0.5f * v * (1.0f + erff(v * 0.70710678118f));
        size_t o = (size_t)(rbase + j) * N + col;
        if (resid) v += resid[o];
        r4[j] = v;
        if (OBF) outb[o] = __float2bfloat16(v);
        else     outf[o] = v;
      }
      if (VT && col >= 2 * Dv) {
        int hh = (col - 2 * Dv) >> 6, dd = (col - 2 * Dv) & 63;
        int bb = rbase >> 10, t0 = rbase & 1023;
        short4v pk = {f2bf(r4[0]), f2bf(r4[1]), f2bf(r4[2]), f2bf(r4[3])};
        *(short4v*)(vt + (((size_t)(bb * Hv + hh) * HDv + dd) << 10) + t0) = pk;
      }
    }
  }
}

__global__ __launch_bounds__(256) void qkv_gemm_kernel(const __hip_bfloat16* A,
                                                       const __hip_bfloat16* Wt,
                                                       const float* bias,
                                                       void* outv, __hip_bfloat16* vt,
                                                       int M, int N, int K) {
  gemm64_body<false, true, true>(A, Wt, bias, nullptr, outv, vt, M, N, K);
}
__global__ __launch_bounds__(256) void proj_gemm_kernel(const __hip_bfloat16* A,
                                                        const __hip_bfloat16* Wt,
                                                        const float* bias,
                                                        const float* resid, float* out,
                                                        int M, int N, int K) {
  gemm64_body<false, false, false>(A, Wt, bias, resid, out, nullptr, M, N, K);
}
__global__ __launch_bounds__(256) void fcproj_gemm_kernel(const __hip_bfloat16* A,
                                                          const __hip_bfloat16* Wt,
                                                          const float* bias,
                                                          const float* resid, float* out,
                                                          int M, int N, int K) {
  gemm64_body<false, false, false>(A, Wt, bias, resid, out, nullptr, M, N, K);
}

// ---------------- fc GEMM: 128x64 tile, BK=64, swizzled, 2-phase dbuf ------
// A-panel (128 rows) staged once per 64-col block -> halves A staging traffic
// vs 64^2 at N=3072. 4 waves (2x2), per-wave 64x32 out (acc[4][2], 32 VGPR).
// LDS 48KB -> 3 blocks/CU. Same proven K-loop order + epilogue pattern.
__global__ __launch_bounds__(256) void fc_gemm_kernel(const __hip_bfloat16* __restrict__ A,
                                                      const __hip_bfloat16* __restrict__ Wt,
                                                      const float* __restrict__ bias,
                                                      void* __restrict__ outv,
                                                      int M, int N, int K) {
  __shared__ short As[2][8192];   // 128 x 64
  __shared__ short Bs[2][4096];   // 64 x 64
  int nwg = gridDim.x * gridDim.y;
  int wgid = xcd_remap(blockIdx.y * gridDim.x + blockIdx.x, nwg);
  int m0 = (wgid % gridDim.x) * 128, n0 = (wgid / gridDim.x) * 64;

  int tid = threadIdx.x;
  int w = tid >> 6, lane = tid & 63;
  int wr = w >> 1, wc = w & 1;
  int lr = lane & 15, lk = lane >> 4;

  f32x4 acc[4][2];
  #pragma unroll
  for (int m = 0; m < 4; ++m)
    #pragma unroll
    for (int n = 0; n < 2; ++n) acc[m][n] = (f32x4){0.f, 0.f, 0.f, 0.f};

  auto stg = [&](int k0, int p) {
    #pragma unroll
    for (int e = 0; e < 4; ++e) {          // A: 128x64 = 1024 granules
      int idx2 = e * 256 + tid;
      int r = idx2 >> 3, g = idx2 & 7;
      int gs = (g ^ (r & 7)) * 8;
      gld16(A + (size_t)(m0 + r) * K + k0 + gs, &As[p][idx2 * 8]);
    }
    #pragma unroll
    for (int e = 0; e < 2; ++e) {          // B: 64x64 = 512 granules
      int idx2 = e * 256 + tid;
      int r = idx2 >> 3, g = idx2 & 7;
      int gs = (g ^ (r & 7)) * 8;
      gld16(Wt + (size_t)(n0 + r) * K + k0 + gs, &Bs[p][idx2 * 8]);
    }
  };

  stg(0, 0);
  __syncthreads();
  int NK = K >> 6;
  for (int kt = 0; kt < NK; ++kt) {
    int p = kt & 1;
    if (kt + 1 < NK) stg((kt + 1) << 6, p ^ 1);
    #pragma unroll
    for (int kf = 0; kf < 2; ++kf) {
      bf16x8 af[4], bf[2];
      #pragma unroll
      for (int m = 0; m < 4; ++m) {
        int row = wr * 64 + m * 16 + lr;
        af[m] = *(const bf16x8*)(&As[p][row * 64 + (((kf * 4 + lk) ^ (row & 7)) * 8)]);
      }
      #pragma unroll
      for (int n = 0; n < 2; ++n) {
        int row = wc * 32 + n * 16 + lr;
        bf[n] = *(const bf16x8*)(&Bs[p][row * 64 + (((kf * 4 + lk) ^ (row & 7)) * 8)]);
      }
      #pragma unroll
      for (int m = 0; m < 4; ++m)
        #pragma unroll
        for (int n = 0; n < 2; ++n)
          acc[m][n] = __builtin_amdgcn_mfma_f32_16x16x32_bf16(af[m], bf[n], acc[m][n], 0, 0, 0);
    }
    __syncthreads();
  }

  int row0 = m0 + wr * 64, col0 = n0 + wc * 32;
  __hip_bfloat16* outb = (__hip_bfloat16*)outv;
  #pragma unroll
  for (int n = 0; n < 2; ++n) {
    int col = col0 + n * 16 + lr;
    float bv = bias[col];
    #pragma unroll
    for (int m = 0; m < 4; ++m) {
      int rbase = row0 + m * 16 + lk * 4;
      #pragma unroll
      for (int j = 0; j < 4; ++j) {
        float v = acc[m][n][j] + bv;
        v = 0.5f * v * (1.0f + erff(v * 0.70710678118f));
        outb[(size_t)(rbase + j) * N + col] = __float2bfloat16(v);
      }
    }
  }
}

// ---------------- 256x256 4-phase counted-vmcnt GEMM (head) ---------------
// Round-6/8 proven schedule: prologue vmcnt(4)+barrier, loop vmcnt(4),
// phantom stages keep the ledger uniform through the final tile.
__global__ __launch_bounds__(512, 2) void gemm256_kernel(const __hip_bfloat16* __restrict__ A,
                                                         const __hip_bfloat16* __restrict__ Wt,
                                                         float* __restrict__ out,
                                                         int N, int K) {
  __shared__ short lds[65536];   // 128 KB
  int nwg = gridDim.x * gridDim.y;
  int wgid = xcd_remap(blockIdx.y * gridDim.x + blockIdx.x, nwg);
  int m0 = (wgid % gridDim.x) * 256, n0 = (wgid / gridDim.x) * 256;

  int tid = threadIdx.x;
  int w = tid >> 6, lane = tid & 63;
  int wr = w >> 2, wc = w & 3;          // 2 x 4 waves
  int lr = lane & 15, lk = lane >> 4;

  f32x4 acc[8][4];
  #pragma unroll
  for (int m = 0; m < 8; ++m)
    #pragma unroll
    for (int n = 0; n < 4; ++n) acc[m][n] = (f32x4){0.f, 0.f, 0.f, 0.f};

  int NT = K >> 6;

  auto stage = [&](int tau, int h) {
    int tsrc = tau < NT ? tau : NT - 1;       // phantom: re-read last tile
    const __hip_bfloat16* mat;
    size_t rb; int lofs;
    if (h == 0)      { mat = A;  rb = (size_t)m0;       lofs = 0; }
    else if (h == 1) { mat = Wt; rb = (size_t)n0;       lofs = 16384; }
    else if (h == 2) { mat = Wt; rb = (size_t)n0 + 128; lofs = 24576; }
    else             { mat = A;  rb = (size_t)m0 + 128; lofs = 8192; }
    short* lb = lds + (tau & 1) * 32768 + lofs;   // parity of REQUESTED tile
    #pragma unroll
    for (int e = 0; e < 2; ++e) {
      int idx = e * 512 + tid;
      int r = idx >> 3, g = idx & 7;
      gld16(mat + (rb + r) * (size_t)K + tsrc * 64 + ((g ^ (r & 7)) * 8), lb + idx * 8);
    }
  };

  stage(0, 0); stage(0, 1); stage(0, 2); stage(0, 3);
  asm volatile("s_waitcnt vmcnt(4)" ::: "memory");
  asm volatile("s_barrier" ::: "memory");

  for (int tau = 0; tau < NT; ++tau) {
    const short* bufA = lds + (tau & 1) * 32768;
    const short* bufB = bufA + 16384;
    #pragma unroll
    for (int q = 0; q < 4; ++q) {
      stage(tau + 1, q);
      asm volatile("s_waitcnt vmcnt(4)" ::: "memory");
      int qm = q >> 1, qn = q & 1;
      const short* ab = bufA + qm * 8192;
      const short* bb = bufB + qn * 8192;
      bf16x8 af[4][2], bf[2][2];
      #pragma unroll
      for (int mi = 0; mi < 4; ++mi) {
        int ra = wr * 64 + mi * 16 + lr;
        #pragma unroll
        for (int kf = 0; kf < 2; ++kf)
          af[mi][kf] = *(const bf16x8*)(ab + ra * 64 + (((kf * 4 + lk) ^ (ra & 7)) * 8));
      }
      #pragma unroll
      for (int ni = 0; ni < 2; ++ni) {
        int rb2 = wc * 32 + ni * 16 + lr;
        #pragma unroll
        for (int kf = 0; kf < 2; ++kf)
          bf[ni][kf] = *(const bf16x8*)(bb + rb2 * 64 + (((kf * 4 + lk) ^ (rb2 & 7)) * 8));
      }
      asm volatile("s_barrier" ::: "memory");
      __builtin_amdgcn_s_setprio(1);
      #pragma unroll
      for (int mi = 0; mi < 4; ++mi)
        #pragma unroll
        for (int ni = 0; ni < 2; ++ni)
          #pragma unroll
          for (int kf = 0; kf < 2; ++kf)
            acc[qm * 4 + mi][qn * 2 + ni] = __builtin_amdgcn_mfma_f32_16x16x32_bf16(
                af[mi][kf], bf[ni][kf], acc[qm * 4 + mi][qn * 2 + ni], 0, 0, 0);
      __builtin_amdgcn_s_setprio(0);
      asm volatile("s_barrier" ::: "memory");
    }
  }

  #pragma unroll
  for (int gm = 0; gm < 8; ++gm) {
    int row = m0 + (gm >> 2) * 128 + wr * 64 + (gm & 3) * 16 + lk * 4;
    #pragma unroll
    for (int gn = 0; gn < 4; ++gn) {
      int col = n0 + (gn >> 1) * 128 + wc * 32 + (gn & 1) * 16 + lr;
      #pragma unroll
      for (int j = 0; j < 4; ++j)
        out[(size_t)(row + j) * N + col] = acc[gm][gn][j];
    }
  }
}

// ---------------- MFMA flash attention (K/V dbuf + setprio, LPT order) -----
__global__ __launch_bounds__(256) void attn_kernel(const __hip_bfloat16* __restrict__ qkv,
                                                   const __hip_bfloat16* __restrict__ vt,
                                                   __hip_bfloat16* __restrict__ y) {
  __shared__ short Ks[2][4096];
  __shared__ short Vts[2][4096];
  __shared__ short Ps[4][1024];
  int lin = blockIdx.x;
  int bh = lin % 24;
  int b = bh / Hv, h = bh % Hv;
  int qb = (Tv / 64 - 1 - lin / 24) * 64;
  int tid = threadIdx.x;
  int w = tid >> 6, l = tid & 63;
  int lr = l & 15, lk = l >> 4;

  bf16x8 aq[2];
  {
    const __hip_bfloat16* qp = qkv + ((size_t)(b * Tv + qb + w * 16 + lr)) * 3 * Dv + h * HDv + lk * 8;
    aq[0] = *(const bf16x8*)qp;
    aq[1] = *(const bf16x8*)(qp + 32);
  }

  f32x4 o[4];
  #pragma unroll
  for (int n = 0; n < 4; ++n) o[n] = (f32x4){0.f, 0.f, 0.f, 0.f};
  float mrow[4] = {-1e30f, -1e30f, -1e30f, -1e30f};
  float lrow[4] = {0.f, 0.f, 0.f, 0.f};

  int r8 = l >> 3, c8 = l & 7;
  int nt = qb / 64 + 1;

  auto stageKV = [&](int kt2, int p) {
    int kbase = kt2 * 64;
    #pragma unroll
    for (int e = 0; e < 2; ++e) {
      int r0 = w * 16 + e * 8;
      int rK = r0 + r8;
      int csK = c8 ^ (rK & 7);
      gld16(qkv + ((size_t)(b * Tv + kbase + rK)) * 3 * Dv + Dv + h * HDv + csK * 8,
            &Ks[p][r0 * 64]);
      gld16(vt + ((size_t)((b * Hv + h) * HDv + rK)) * Tv + kbase + csK * 8,
            &Vts[p][r0 * 64]);
    }
  };

  stageKV(0, 0);
  __syncthreads();

  for (int kt = 0; kt < nt; ++kt) {
    int p = kt & 1;
    if (kt + 1 < nt) stageKV(kt + 1, p ^ 1);

    f32x4 s[4];
    #pragma unroll
    for (int n = 0; n < 4; ++n) s[n] = (f32x4){0.f, 0.f, 0.f, 0.f};
    __builtin_amdgcn_s_setprio(1);
    #pragma unroll
    for (int kf = 0; kf < 2; ++kf)
      #pragma unroll
      for (int nf = 0; nf < 4; ++nf) {
        int row = nf * 16 + lr;
        int g = (kf * 4 + lk) ^ (row & 7);
        bf16x8 bk = *(const bf16x8*)(&Ks[p][row * 64 + g * 8]);
        s[nf] = __builtin_amdgcn_mfma_f32_16x16x32_bf16(aq[kf], bk, s[nf], 0, 0, 0);
      }
    __builtin_amdgcn_s_setprio(0);
    #pragma unroll
    for (int nf = 0; nf < 4; ++nf)
      #pragma unroll
      for (int j = 0; j < 4; ++j) s[nf][j] *= 0.125f;

    if (kt == nt - 1) {
      #pragma unroll
      for (int nf = 0; nf < 4; ++nf) {
        int kl = nf * 16 + lr;
        #pragma unroll
        for (int j = 0; j < 4; ++j)
          if (kl > w * 16 + lk * 4 + j) s[nf][j] = -1e30f;
      }
    }

    float sc[4];
    #pragma unroll
    for (int j = 0; j < 4; ++j) {
      float pm = fmaxf(fmaxf(s[0][j], s[1][j]), fmaxf(s[2][j], s[3][j]));
      pm = fmaxf(pm, __shfl_xor(pm, 1, 64));
      pm = fmaxf(pm, __shfl_xor(pm, 2, 64));
      pm = fmaxf(pm, __shfl_xor(pm, 4, 64));
      pm = fmaxf(pm, __shfl_xor(pm, 8, 64));
      float mn = fmaxf(mrow[j], pm);
      sc[j] = __expf(mrow[j] - mn);
      mrow[j] = mn;
    }
    #pragma unroll
    for (int j = 0; j < 4; ++j) {
      float ls = 0.f;
      #pragma unroll
      for (int nf = 0; nf < 4; ++nf) {
        float p2 = __expf(s[nf][j] - mrow[j]);
        s[nf][j] = p2;
        ls += p2;
      }
      ls += __shfl_xor(ls, 1, 64);
      ls += __shfl_xor(ls, 2, 64);
      ls += __shfl_xor(ls, 4, 64);
      ls += __shfl_xor(ls, 8, 64);
      lrow[j] = lrow[j] * sc[j] + ls;
    }
    #pragma unroll
    for (int n = 0; n < 4; ++n)
      #pragma unroll
      for (int j = 0; j < 4; ++j) o[n][j] *= sc[j];

    short* pw = Ps[w];
    #pragma unroll
    for (int nf = 0; nf < 4; ++nf)
      #pragma unroll
      for (int j = 0; j < 4; ++j) {
        int ql = lk * 4 + j, k = nf * 16 + lr;
        pw[ql * 64 + (((k >> 3) ^ (ql & 7)) * 8) + (k & 7)] = f2bf(s[nf][j]);
      }
    bf16x8 pa[2];
    #pragma unroll
    for (int kf = 0; kf < 2; ++kf) {
      int g = (kf * 4 + lk) ^ (lr & 7);
      pa[kf] = *(const bf16x8*)(pw + lr * 64 + g * 8);
    }
    __builtin_amdgcn_s_setprio(1);
    #pragma unroll
    for (int kf = 0; kf < 2; ++kf)
      #pragma unroll
      for (int nf = 0; nf < 4; ++nf) {
        int d = nf * 16 + lr;
        int g = (kf * 4 + lk) ^ (d & 7);
        bf16x8 bv = *(const bf16x8*)(&Vts[p][d * 64 + g * 8]);
        o[nf] = __builtin_amdgcn_mfma_f32_16x16x32_bf16(pa[kf], bv, o[nf], 0, 0, 0);
      }
    __builtin_amdgcn_s_setprio(0);
    __syncthreads();   // drains next-tile stage + WAR for buf p
  }

  #pragma unroll
  for (int j = 0; j < 4; ++j) lrow[j] = 1.f / lrow[j];
  #pragma unroll
  for (int nf = 0; nf < 4; ++nf)
    #pragma unroll
    for (int j = 0; j < 4; ++j) {
      size_t oidx = ((size_t)(b * Tv + qb + w * 16 + lk * 4 + j)) * Dv + h * HDv + nf * 16 + lr;
      y[oidx] = __float2bfloat16(o[nf][j] * lrow[j]);
    }
}

extern "C" void kernel_launch(void* const* d_in, const int* in_sizes, int n_in,
                              void* d_out, int out_size, void* d_ws, size_t ws_size,
                              hipStream_t stream) {
  const int*   idx      = (const int*)  d_in[0];
  const float* wte      = (const float*)d_in[1];
  const float* wpe      = (const float*)d_in[2];
  const float* ln1_w    = (const float*)d_in[3];
  const float* ln1_b    = (const float*)d_in[4];
  const float* attn_w   = (const float*)d_in[5];
  const float* attn_b   = (const float*)d_in[6];
  const float* proj_w   = (const float*)d_in[7];
  const float* proj_b   = (const float*)d_in[8];
  const float* ln2_w    = (const float*)d_in[9];
  const float* ln2_b    = (const float*)d_in[10];
  const float* fc_w     = (const float*)d_in[11];
  const float* fc_b     = (const float*)d_in[12];
  const float* fcproj_w = (const float*)d_in[13];
  const float* fcproj_b = (const float*)d_in[14];
  const float* lnf_w    = (const float*)d_in[15];
  const float* lnf_b    = (const float*)d_in[16];
  const float* head_w   = (const float*)d_in[17];
  float* outp = (float*)d_out;

  char* w8 = (char*)d_ws;
  float*          x    = (float*)w8;                          // 2048*768 f32
  __hip_bfloat16* h    = (__hip_bfloat16*)(w8 + 6291456);     // 2048*768 bf16
  __hip_bfloat16* qkv  = (__hip_bfloat16*)(w8 + 9437184);     // 2048*2304 bf16
  __hip_bfloat16* m4   = qkv;                                 // 2048*3072 bf16 alias
  __hip_bfloat16* y    = (__hip_bfloat16*)(w8 + 22020096);    // 2048*768 bf16
  __hip_bfloat16* vt   = (__hip_bfloat16*)(w8 + 25165824);    // B*H*64*1024 bf16
  __hip_bfloat16* wbuf = (__hip_bfloat16*)(w8 + 28311552);    // weight staging

  __hip_bfloat16* wb_attn   = wbuf;
  __hip_bfloat16* wb_proj   = wb_attn + (size_t)768 * 2304;
  __hip_bfloat16* wb_fc     = wb_proj + (size_t)768 * 768;
  __hip_bfloat16* wb_fcproj = wb_fc   + (size_t)768 * 3072;

  embed_kernel<<<(MROWS * Dv / 4 + 255) / 256, 256, 0, stream>>>(idx, wte, wpe, x);

  for (int l = 0; l < Lv; ++l) {
    ln_tcast4_kernel<<<MROWS + 6912, 256, 0, stream>>>(
        x, ln1_w + (size_t)l * Dv, ln1_b + (size_t)l * Dv, h,
        attn_w   + (size_t)l * Dv * 3 * Dv,
        proj_w   + (size_t)l * Dv * Dv,
        fc_w     + (size_t)l * Dv * 4 * Dv,
        fcproj_w + (size_t)l * 4 * Dv * Dv,
        wb_attn, wb_proj, wb_fc, wb_fcproj);
    qkv_gemm_kernel<<<dim3(MROWS / 64, 3 * Dv / 64), 256, 0, stream>>>(
        h, wb_attn, attn_b + (size_t)l * 3 * Dv, qkv, vt, MROWS, 3 * Dv, Dv);
    attn_kernel<<<(Tv / 64) * Hv * Bv, 256, 0, stream>>>(qkv, vt, y);
    proj_gemm_kernel<<<dim3(MROWS / 64, Dv / 64), 256, 0, stream>>>(
        y, wb_proj, proj_b + (size_t)l * Dv, x, x, MROWS, Dv, Dv);
    ln_kernel<<<MROWS, 256, 0, stream>>>(x, ln2_w + (size_t)l * Dv, ln2_b + (size_t)l * Dv, h);
    fc_gemm_kernel<<<dim3(MROWS / 128, 4 * Dv / 64), 256, 0, stream>>>(
        h, wb_fc, fc_b + (size_t)l * 4 * Dv, m4, MROWS, 4 * Dv, Dv);
    fcproj_gemm_kernel<<<dim3(MROWS / 64, Dv / 64), 256, 0, stream>>>(
        m4, wb_fcproj, fcproj_b + (size_t)l * Dv, x, x, MROWS, Dv, 4 * Dv);
  }

  lnf_tcast_kernel<<<MROWS + 24000, 256, 0, stream>>>(
      x, lnf_w, lnf_b, h, head_w, wbuf);
  gemm256_kernel<<<dim3(MROWS / 256, Vv / 256), 512, 0, stream>>>(
      h, wbuf, outp, Vv, Dv);
}

// Round 14
// 959.326 us; speedup vs baseline: 1.2136x; 1.0297x over previous
//
#include <hip/hip_runtime.h>
#include <hip/hip_bf16.h>
#include <math.h>

static constexpr int Bv = 2, Tv = 1024, Dv = 768, Hv = 12, Lv = 6, Vv = 32000, HDv = 64;
static constexpr int MROWS = Bv * Tv;   // 2048

typedef __attribute__((ext_vector_type(8))) short bf16x8;
typedef __attribute__((ext_vector_type(8))) short short8;
typedef __attribute__((ext_vector_type(4))) short short4v;
typedef __attribute__((ext_vector_type(4))) float f32x4;

typedef __attribute__((address_space(1))) const void gvoid;
typedef __attribute__((address_space(3))) void svoid;
__device__ __forceinline__ void gld16(const void* g, void* s) {
  __builtin_amdgcn_global_load_lds((gvoid*)g, (svoid*)s, 16, 0, 0);
}
__device__ __forceinline__ short f2bf(float v) {
  __hip_bfloat16 hb = __float2bfloat16(v);
  return *reinterpret_cast<short*>(&hb);
}
// bijective XCD-chunk remap (m204)
__device__ __forceinline__ int xcd_remap(int lin, int nwg) {
  int q = nwg >> 3, r = nwg & 7;
  int xcd = lin & 7, idx = lin >> 3;
  return (xcd < r ? xcd * (q + 1) : r * (q + 1) + (xcd - r) * q) + idx;
}

// ---------------- embedding ----------------
__global__ __launch_bounds__(256) void embed_kernel(const int* __restrict__ idx,
                                                    const float* __restrict__ wte,
                                                    const float* __restrict__ wpe,
                                                    float* __restrict__ x) {
  int i4 = blockIdx.x * 256 + threadIdx.x;
  int total = MROWS * Dv / 4;
  if (i4 >= total) return;
  int d4 = (i4 % (Dv / 4)) * 4;
  int bt = i4 / (Dv / 4);
  int t  = bt % Tv;
  int id = idx[bt];
  float4 a = *(const float4*)(wte + (size_t)id * Dv + d4);
  float4 p = *(const float4*)(wpe + (size_t)t  * Dv + d4);
  a.x += p.x; a.y += p.y; a.z += p.z; a.w += p.w;
  *(float4*)(x + (size_t)bt * Dv + d4) = a;
}

// ---------------- layernorm body: fp32 in -> bf16 out ----------------
__device__ __forceinline__ void ln_body(const float* __restrict__ x,
                                        const float* __restrict__ w,
                                        const float* __restrict__ b,
                                        __hip_bfloat16* __restrict__ out, int row) {
  __shared__ float red[8];
  const float* xr = x + (size_t)row * Dv;
  int tid = threadIdx.x;
  float v0 = xr[tid], v1 = xr[tid + 256], v2 = xr[tid + 512];
  int wid = tid >> 6, lane = tid & 63;

  float s = v0 + v1 + v2;
  #pragma unroll
  for (int off = 1; off < 64; off <<= 1) s += __shfl_xor(s, off, 64);
  if (lane == 0) red[wid] = s;
  __syncthreads();
  s = red[0] + red[1] + red[2] + red[3];
  float mu = s * (1.0f / Dv);

  float d0 = v0 - mu, d1 = v1 - mu, d2 = v2 - mu;
  float q = d0 * d0 + d1 * d1 + d2 * d2;
  #pragma unroll
  for (int off = 1; off < 64; off <<= 1) q += __shfl_xor(q, off, 64);
  if (lane == 0) red[4 + wid] = q;
  __syncthreads();
  q = red[4] + red[5] + red[6] + red[7];
  float rs = rsqrtf(q * (1.0f / Dv) + 1e-5f);

  __hip_bfloat16* orow = out + (size_t)row * Dv;
  orow[tid]       = __float2bfloat16(d0 * rs * w[tid]       + b[tid]);
  orow[tid + 256] = __float2bfloat16(d1 * rs * w[tid + 256] + b[tid + 256]);
  orow[tid + 512] = __float2bfloat16(d2 * rs * w[tid + 512] + b[tid + 512]);
}

__global__ __launch_bounds__(256) void ln_kernel(const float* __restrict__ x,
                                                 const float* __restrict__ w,
                                                 const float* __restrict__ b,
                                                 __hip_bfloat16* __restrict__ out) {
  ln_body(x, w, b, out, blockIdx.x);
}

// ---------------- transpose+cast body ----------------
__device__ __forceinline__ void tcast_body(const float* __restrict__ W,
                                           __hip_bfloat16* __restrict__ Wt,
                                           int K, int N, int k0, int n0) {
  __shared__ float tile[32][33];
  int tx = threadIdx.x & 31, ty = threadIdx.x >> 5;
  #pragma unroll
  for (int r = 0; r < 32; r += 8)
    tile[ty + r][tx] = W[(size_t)(k0 + ty + r) * N + n0 + tx];
  __syncthreads();
  #pragma unroll
  for (int r = 0; r < 32; r += 8)
    Wt[(size_t)(n0 + ty + r) * K + k0 + tx] = __float2bfloat16(tile[tx][ty + r]);
}

// ---------------- fused ln1 + 4-weight tcast (per layer) -------------------
__global__ __launch_bounds__(256) void ln_tcast4_kernel(const float* __restrict__ x,
                                                        const float* __restrict__ lw,
                                                        const float* __restrict__ lb,
                                                        __hip_bfloat16* __restrict__ h,
                                                        const float* __restrict__ s0,
                                                        const float* __restrict__ s1,
                                                        const float* __restrict__ s2,
                                                        const float* __restrict__ s3,
                                                        __hip_bfloat16* __restrict__ d0,
                                                        __hip_bfloat16* __restrict__ d1,
                                                        __hip_bfloat16* __restrict__ d2,
                                                        __hip_bfloat16* __restrict__ d3) {
  int blk = blockIdx.x;
  if (blk < MROWS) { ln_body(x, lw, lb, h, blk); return; }
  int lin = blk - MROWS;
  const float* W; __hip_bfloat16* Wt; int K, N, loc;
  if (lin < 1728)      { W = s0; Wt = d0; K = 768;  N = 2304; loc = lin; }
  else if (lin < 2304) { W = s1; Wt = d1; K = 768;  N = 768;  loc = lin - 1728; }
  else if (lin < 4608) { W = s2; Wt = d2; K = 768;  N = 3072; loc = lin - 2304; }
  else                 { W = s3; Wt = d3; K = 3072; N = 768;  loc = lin - 4608; }
  int nb = N / 32;
  tcast_body(W, Wt, K, N, (loc / nb) * 32, (loc % nb) * 32);
}

// ---------------- fused lnf + head tcast -----------------------------------
__global__ __launch_bounds__(256) void lnf_tcast_kernel(const float* __restrict__ x,
                                                        const float* __restrict__ lw,
                                                        const float* __restrict__ lb,
                                                        __hip_bfloat16* __restrict__ h,
                                                        const float* __restrict__ head_w,
                                                        __hip_bfloat16* __restrict__ wb) {
  int blk = blockIdx.x;
  if (blk < MROWS) { ln_body(x, lw, lb, h, blk); return; }
  int loc = blk - MROWS;                 // 0..23999
  int nb = Vv / 32;                      // 1000
  tcast_body(head_w, wb, Dv, Vv, (loc / nb) * 32, (loc % nb) * 32);
}

// ---------------- 64x64 MFMA GEMM body (BK=64, swizzled, 2-phase dbuf) -----
template <bool GELU, bool OBF, bool VT>
__device__ __forceinline__ void gemm64_body(const __hip_bfloat16* __restrict__ A,
                                            const __hip_bfloat16* __restrict__ Wt,
                                            const float* __restrict__ bias,
                                            const float* __restrict__ resid,
                                            void* __restrict__ outv,
                                            __hip_bfloat16* __restrict__ vt,
                                            int M, int N, int K) {
  __shared__ short As[2][4096];
  __shared__ short Bs[2][4096];
  int nwg = gridDim.x * gridDim.y;
  int wgid = xcd_remap(blockIdx.y * gridDim.x + blockIdx.x, nwg);
  int m0 = (wgid % gridDim.x) * 64, n0 = (wgid / gridDim.x) * 64;

  int tid = threadIdx.x;
  int w = tid >> 6, lane = tid & 63;
  int wr = w >> 1, wc = w & 1;
  int lr = lane & 15, lk = lane >> 4;
  int rsub = lane >> 3, go = lane & 7;

  f32x4 acc[2][2];
  #pragma unroll
  for (int m = 0; m < 2; ++m)
    #pragma unroll
    for (int n = 0; n < 2; ++n) acc[m][n] = (f32x4){0.f, 0.f, 0.f, 0.f};

  auto stg = [&](int k0, int p) {
    #pragma unroll
    for (int e = 0; e < 2; ++e) {
      int row = w * 16 + e * 8 + rsub;
      int gs = (go ^ rsub) * 8;
      gld16(A  + (size_t)(m0 + row) * K + k0 + gs, &As[p][w * 1024 + e * 512]);
      gld16(Wt + (size_t)(n0 + row) * K + k0 + gs, &Bs[p][w * 1024 + e * 512]);
    }
  };

  stg(0, 0);
  __syncthreads();
  int NK = K >> 6;
  for (int kt = 0; kt < NK; ++kt) {
    int p = kt & 1;
    if (kt + 1 < NK) stg((kt + 1) << 6, p ^ 1);
    #pragma unroll
    for (int kf = 0; kf < 2; ++kf) {
      bf16x8 af[2], bf[2];
      #pragma unroll
      for (int m = 0; m < 2; ++m) {
        int row = wr * 32 + m * 16 + lr;
        af[m] = *(const bf16x8*)(&As[p][row * 64 + (((kf * 4 + lk) ^ (row & 7)) * 8)]);
      }
      #pragma unroll
      for (int n = 0; n < 2; ++n) {
        int row = wc * 32 + n * 16 + lr;
        bf[n] = *(const bf16x8*)(&Bs[p][row * 64 + (((kf * 4 + lk) ^ (row & 7)) * 8)]);
      }
      #pragma unroll
      for (int m = 0; m < 2; ++m)
        #pragma unroll
        for (int n = 0; n < 2; ++n)
          acc[m][n] = __builtin_amdgcn_mfma_f32_16x16x32_bf16(af[m], bf[n], acc[m][n], 0, 0, 0);
    }
    __syncthreads();
  }

  int row0 = m0 + wr * 32, col0 = n0 + wc * 32;
  float* outf = (float*)outv;
  __hip_bfloat16* outb = (__hip_bfloat16*)outv;
  #pragma unroll
  for (int n = 0; n < 2; ++n) {
    int col = col0 + n * 16 + lr;
    float bv = bias ? bias[col] : 0.f;
    #pragma unroll
    for (int m = 0; m < 2; ++m) {
      int rbase = row0 + m * 16 + lk * 4;
      float r4[4];
      #pragma unroll
      for (int j = 0; j < 4; ++j) {
        float v = acc[m][n][j] + bv;
        if (GELU) v = 0.5f * v * (1.0f + erff(v * 0.70710678118f));
        size_t o = (size_t)(rbase + j) * N + col;
        if (resid) v += resid[o];
        r4[j] = v;
        if (OBF) outb[o] = __float2bfloat16(v);
        else     outf[o] = v;
      }
      if (VT && col >= 2 * Dv) {
        int hh = (col - 2 * Dv) >> 6, dd = (col - 2 * Dv) & 63;
        int bb = rbase >> 10, t0 = rbase & 1023;
        short4v pk = {f2bf(r4[0]), f2bf(r4[1]), f2bf(r4[2]), f2bf(r4[3])};
        *(short4v*)(vt + (((size_t)(bb * Hv + hh) * HDv + dd) << 10) + t0) = pk;
      }
    }
  }
}

__global__ __launch_bounds__(256) void proj_gemm_kernel(const __hip_bfloat16* A,
                                                        const __hip_bfloat16* Wt,
                                                        const float* bias,
                                                        const float* resid, float* out,
                                                        int M, int N, int K) {
  gemm64_body<false, false, false>(A, Wt, bias, resid, out, nullptr, M, N, K);
}
__global__ __launch_bounds__(256) void fcproj_gemm_kernel(const __hip_bfloat16* A,
                                                          const __hip_bfloat16* Wt,
                                                          const float* bias,
                                                          const float* resid, float* out,
                                                          int M, int N, int K) {
  gemm64_body<false, false, false>(A, Wt, bias, resid, out, nullptr, M, N, K);
}

// ---------------- 128x64 MFMA GEMM body (BK=64, swizzled, 2-phase dbuf) ----
// For wide-N GEMMs (qkv N=2304, fc N=3072): 128-row A-panel staged once per
// 64-col block halves A staging vs 64^2. 4 waves (2x2), per-wave 64x32 out
// (acc[4][2], 32 VGPR). LDS 48KB -> 3 blocks/CU. Proven round-13 structure;
// epilogue templated <GELU, VT> (bf16 out, optional V-transpose scatter).
template <bool GELU, bool VT>
__device__ __forceinline__ void gemm128x64_body(const __hip_bfloat16* __restrict__ A,
                                                const __hip_bfloat16* __restrict__ Wt,
                                                const float* __restrict__ bias,
                                                void* __restrict__ outv,
                                                __hip_bfloat16* __restrict__ vt,
                                                int M, int N, int K) {
  __shared__ short As[2][8192];   // 128 x 64
  __shared__ short Bs[2][4096];   // 64 x 64
  int nwg = gridDim.x * gridDim.y;
  int wgid = xcd_remap(blockIdx.y * gridDim.x + blockIdx.x, nwg);
  int m0 = (wgid % gridDim.x) * 128, n0 = (wgid / gridDim.x) * 64;

  int tid = threadIdx.x;
  int w = tid >> 6, lane = tid & 63;
  int wr = w >> 1, wc = w & 1;
  int lr = lane & 15, lk = lane >> 4;

  f32x4 acc[4][2];
  #pragma unroll
  for (int m = 0; m < 4; ++m)
    #pragma unroll
    for (int n = 0; n < 2; ++n) acc[m][n] = (f32x4){0.f, 0.f, 0.f, 0.f};

  auto stg = [&](int k0, int p) {
    #pragma unroll
    for (int e = 0; e < 4; ++e) {          // A: 128x64 = 1024 granules
      int idx2 = e * 256 + tid;
      int r = idx2 >> 3, g = idx2 & 7;
      int gs = (g ^ (r & 7)) * 8;
      gld16(A + (size_t)(m0 + r) * K + k0 + gs, &As[p][idx2 * 8]);
    }
    #pragma unroll
    for (int e = 0; e < 2; ++e) {          // B: 64x64 = 512 granules
      int idx2 = e * 256 + tid;
      int r = idx2 >> 3, g = idx2 & 7;
      int gs = (g ^ (r & 7)) * 8;
      gld16(Wt + (size_t)(n0 + r) * K + k0 + gs, &Bs[p][idx2 * 8]);
    }
  };

  stg(0, 0);
  __syncthreads();
  int NK = K >> 6;
  for (int kt = 0; kt < NK; ++kt) {
    int p = kt & 1;
    if (kt + 1 < NK) stg((kt + 1) << 6, p ^ 1);
    #pragma unroll
    for (int kf = 0; kf < 2; ++kf) {
      bf16x8 af[4], bf[2];
      #pragma unroll
      for (int m = 0; m < 4; ++m) {
        int row = wr * 64 + m * 16 + lr;
        af[m] = *(const bf16x8*)(&As[p][row * 64 + (((kf * 4 + lk) ^ (row & 7)) * 8)]);
      }
      #pragma unroll
      for (int n = 0; n < 2; ++n) {
        int row = wc * 32 + n * 16 + lr;
        bf[n] = *(const bf16x8*)(&Bs[p][row * 64 + (((kf * 4 + lk) ^ (row & 7)) * 8)]);
      }
      #pragma unroll
      for (int m = 0; m < 4; ++m)
        #pragma unroll
        for (int n = 0; n < 2; ++n)
          acc[m][n] = __builtin_amdgcn_mfma_f32_16x16x32_bf16(af[m], bf[n], acc[m][n], 0, 0, 0);
    }
    __syncthreads();
  }

  int row0 = m0 + wr * 64, col0 = n0 + wc * 32;
  __hip_bfloat16* outb = (__hip_bfloat16*)outv;
  #pragma unroll
  for (int n = 0; n < 2; ++n) {
    int col = col0 + n * 16 + lr;
    float bv = bias[col];
    #pragma unroll
    for (int m = 0; m < 4; ++m) {
      int rbase = row0 + m * 16 + lk * 4;
      float r4[4];
      #pragma unroll
      for (int j = 0; j < 4; ++j) {
        float v = acc[m][n][j] + bv;
        if (GELU) v = 0.5f * v * (1.0f + erff(v * 0.70710678118f));
        r4[j] = v;
        outb[(size_t)(rbase + j) * N + col] = __float2bfloat16(v);
      }
      if (VT && col >= 2 * Dv) {
        int hh = (col - 2 * Dv) >> 6, dd = (col - 2 * Dv) & 63;
        int bb = rbase >> 10, t0 = rbase & 1023;
        short4v pk = {f2bf(r4[0]), f2bf(r4[1]), f2bf(r4[2]), f2bf(r4[3])};
        *(short4v*)(vt + (((size_t)(bb * Hv + hh) * HDv + dd) << 10) + t0) = pk;
      }
    }
  }
}

__global__ __launch_bounds__(256) void qkv_gemm_kernel(const __hip_bfloat16* A,
                                                       const __hip_bfloat16* Wt,
                                                       const float* bias,
                                                       void* outv, __hip_bfloat16* vt,
                                                       int M, int N, int K) {
  gemm128x64_body<false, true>(A, Wt, bias, outv, vt, M, N, K);
}
__global__ __launch_bounds__(256) void fc_gemm_kernel(const __hip_bfloat16* A,
                                                      const __hip_bfloat16* Wt,
                                                      const float* bias,
                                                      void* outv, int M, int N, int K) {
  gemm128x64_body<true, false>(A, Wt, bias, outv, nullptr, M, N, K);
}

// ---------------- 256x256 4-phase counted-vmcnt GEMM (head) ---------------
// Round-6/8 proven schedule: prologue vmcnt(4)+barrier, loop vmcnt(4),
// phantom stages keep the ledger uniform through the final tile.
__global__ __launch_bounds__(512, 2) void gemm256_kernel(const __hip_bfloat16* __restrict__ A,
                                                         const __hip_bfloat16* __restrict__ Wt,
                                                         float* __restrict__ out,
                                                         int N, int K) {
  __shared__ short lds[65536];   // 128 KB
  int nwg = gridDim.x * gridDim.y;
  int wgid = xcd_remap(blockIdx.y * gridDim.x + blockIdx.x, nwg);
  int m0 = (wgid % gridDim.x) * 256, n0 = (wgid / gridDim.x) * 256;

  int tid = threadIdx.x;
  int w = tid >> 6, lane = tid & 63;
  int wr = w >> 2, wc = w & 3;          // 2 x 4 waves
  int lr = lane & 15, lk = lane >> 4;

  f32x4 acc[8][4];
  #pragma unroll
  for (int m = 0; m < 8; ++m)
    #pragma unroll
    for (int n = 0; n < 4; ++n) acc[m][n] = (f32x4){0.f, 0.f, 0.f, 0.f};

  int NT = K >> 6;

  auto stage = [&](int tau, int h) {
    int tsrc = tau < NT ? tau : NT - 1;       // phantom: re-read last tile
    const __hip_bfloat16* mat;
    size_t rb; int lofs;
    if (h == 0)      { mat = A;  rb = (size_t)m0;       lofs = 0; }
    else if (h == 1) { mat = Wt; rb = (size_t)n0;       lofs = 16384; }
    else if (h == 2) { mat = Wt; rb = (size_t)n0 + 128; lofs = 24576; }
    else             { mat = A;  rb = (size_t)m0 + 128; lofs = 8192; }
    short* lb = lds + (tau & 1) * 32768 + lofs;   // parity of REQUESTED tile
    #pragma unroll
    for (int e = 0; e < 2; ++e) {
      int idx = e * 512 + tid;
      int r = idx >> 3, g = idx & 7;
      gld16(mat + (rb + r) * (size_t)K + tsrc * 64 + ((g ^ (r & 7)) * 8), lb + idx * 8);
    }
  };

  stage(0, 0); stage(0, 1); stage(0, 2); stage(0, 3);
  asm volatile("s_waitcnt vmcnt(4)" ::: "memory");
  asm volatile("s_barrier" ::: "memory");

  for (int tau = 0; tau < NT; ++tau) {
    const short* bufA = lds + (tau & 1) * 32768;
    const short* bufB = bufA + 16384;
    #pragma unroll
    for (int q = 0; q < 4; ++q) {
      stage(tau + 1, q);
      asm volatile("s_waitcnt vmcnt(4)" ::: "memory");
      int qm = q >> 1, qn = q & 1;
      const short* ab = bufA + qm * 8192;
      const short* bb = bufB + qn * 8192;
      bf16x8 af[4][2], bf[2][2];
      #pragma unroll
      for (int mi = 0; mi < 4; ++mi) {
        int ra = wr * 64 + mi * 16 + lr;
        #pragma unroll
        for (int kf = 0; kf < 2; ++kf)
          af[mi][kf] = *(const bf16x8*)(ab + ra * 64 + (((kf * 4 + lk) ^ (ra & 7)) * 8));
      }
      #pragma unroll
      for (int ni = 0; ni < 2; ++ni) {
        int rb2 = wc * 32 + ni * 16 + lr;
        #pragma unroll
        for (int kf = 0; kf < 2; ++kf)
          bf[ni][kf] = *(const bf16x8*)(bb + rb2 * 64 + (((kf * 4 + lk) ^ (rb2 & 7)) * 8));
      }
      asm volatile("s_barrier" ::: "memory");
      __builtin_amdgcn_s_setprio(1);
      #pragma unroll
      for (int mi = 0; mi < 4; ++mi)
        #pragma unroll
        for (int ni = 0; ni < 2; ++ni)
          #pragma unroll
          for (int kf = 0; kf < 2; ++kf)
            acc[qm * 4 + mi][qn * 2 + ni] = __builtin_amdgcn_mfma_f32_16x16x32_bf16(
                af[mi][kf], bf[ni][kf], acc[qm * 4 + mi][qn * 2 + ni], 0, 0, 0);
      __builtin_amdgcn_s_setprio(0);
      asm volatile("s_barrier" ::: "memory");
    }
  }

  #pragma unroll
  for (int gm = 0; gm < 8; ++gm) {
    int row = m0 + (gm >> 2) * 128 + wr * 64 + (gm & 3) * 16 + lk * 4;
    #pragma unroll
    for (int gn = 0; gn < 4; ++gn) {
      int col = n0 + (gn >> 1) * 128 + wc * 32 + (gn & 1) * 16 + lr;
      #pragma unroll
      for (int j = 0; j < 4; ++j)
        out[(size_t)(row + j) * N + col] = acc[gm][gn][j];
    }
  }
}

// ---------------- MFMA flash attention (K/V dbuf + setprio, LPT order) -----
__global__ __launch_bounds__(256) void attn_kernel(const __hip_bfloat16* __restrict__ qkv,
                                                   const __hip_bfloat16* __restrict__ vt,
                                                   __hip_bfloat16* __restrict__ y) {
  __shared__ short Ks[2][4096];
  __shared__ short Vts[2][4096];
  __shared__ short Ps[4][1024];
  int lin = blockIdx.x;
  int bh = lin % 24;
  int b = bh / Hv, h = bh % Hv;
  int qb = (Tv / 64 - 1 - lin / 24) * 64;
  int tid = threadIdx.x;
  int w = tid >> 6, l = tid & 63;
  int lr = l & 15, lk = l >> 4;

  bf16x8 aq[2];
  {
    const __hip_bfloat16* qp = qkv + ((size_t)(b * Tv + qb + w * 16 + lr)) * 3 * Dv + h * HDv + lk * 8;
    aq[0] = *(const bf16x8*)qp;
    aq[1] = *(const bf16x8*)(qp + 32);
  }

  f32x4 o[4];
  #pragma unroll
  for (int n = 0; n < 4; ++n) o[n] = (f32x4){0.f, 0.f, 0.f, 0.f};
  float mrow[4] = {-1e30f, -1e30f, -1e30f, -1e30f};
  float lrow[4] = {0.f, 0.f, 0.f, 0.f};

  int r8 = l >> 3, c8 = l & 7;
  int nt = qb / 64 + 1;

  auto stageKV = [&](int kt2, int p) {
    int kbase = kt2 * 64;
    #pragma unroll
    for (int e = 0; e < 2; ++e) {
      int r0 = w * 16 + e * 8;
      int rK = r0 + r8;
      int csK = c8 ^ (rK & 7);
      gld16(qkv + ((size_t)(b * Tv + kbase + rK)) * 3 * Dv + Dv + h * HDv + csK * 8,
            &Ks[p][r0 * 64]);
      gld16(vt + ((size_t)((b * Hv + h) * HDv + rK)) * Tv + kbase + csK * 8,
            &Vts[p][r0 * 64]);
    }
  };

  stageKV(0, 0);
  __syncthreads();

  for (int kt = 0; kt < nt; ++kt) {
    int p = kt & 1;
    if (kt + 1 < nt) stageKV(kt + 1, p ^ 1);

    f32x4 s[4];
    #pragma unroll
    for (int n = 0; n < 4; ++n) s[n] = (f32x4){0.f, 0.f, 0.f, 0.f};
    __builtin_amdgcn_s_setprio(1);
    #pragma unroll
    for (int kf = 0; kf < 2; ++kf)
      #pragma unroll
      for (int nf = 0; nf < 4; ++nf) {
        int row = nf * 16 + lr;
        int g = (kf * 4 + lk) ^ (row & 7);
        bf16x8 bk = *(const bf16x8*)(&Ks[p][row * 64 + g * 8]);
        s[nf] = __builtin_amdgcn_mfma_f32_16x16x32_bf16(aq[kf], bk, s[nf], 0, 0, 0);
      }
    __builtin_amdgcn_s_setprio(0);
    #pragma unroll
    for (int nf = 0; nf < 4; ++nf)
      #pragma unroll
      for (int j = 0; j < 4; ++j) s[nf][j] *= 0.125f;

    if (kt == nt - 1) {
      #pragma unroll
      for (int nf = 0; nf < 4; ++nf) {
        int kl = nf * 16 + lr;
        #pragma unroll
        for (int j = 0; j < 4; ++j)
          if (kl > w * 16 + lk * 4 + j) s[nf][j] = -1e30f;
      }
    }

    float sc[4];
    #pragma unroll
    for (int j = 0; j < 4; ++j) {
      float pm = fmaxf(fmaxf(s[0][j], s[1][j]), fmaxf(s[2][j], s[3][j]));
      pm = fmaxf(pm, __shfl_xor(pm, 1, 64));
      pm = fmaxf(pm, __shfl_xor(pm, 2, 64));
      pm = fmaxf(pm, __shfl_xor(pm, 4, 64));
      pm = fmaxf(pm, __shfl_xor(pm, 8, 64));
      float mn = fmaxf(mrow[j], pm);
      sc[j] = __expf(mrow[j] - mn);
      mrow[j] = mn;
    }
    #pragma unroll
    for (int j = 0; j < 4; ++j) {
      float ls = 0.f;
      #pragma unroll
      for (int nf = 0; nf < 4; ++nf) {
        float p2 = __expf(s[nf][j] - mrow[j]);
        s[nf][j] = p2;
        ls += p2;
      }
      ls += __shfl_xor(ls, 1, 64);
      ls += __shfl_xor(ls, 2, 64);
      ls += __shfl_xor(ls, 4, 64);
      ls += __shfl_xor(ls, 8, 64);
      lrow[j] = lrow[j] * sc[j] + ls;
    }
    #pragma unroll
    for (int n = 0; n < 4; ++n)
      #pragma unroll
      for (int j = 0; j < 4; ++j) o[n][j] *= sc[j];

    short* pw = Ps[w];
    #pragma unroll
    for (int nf = 0; nf < 4; ++nf)
      #pragma unroll
      for (int j = 0; j < 4; ++j) {
        int ql = lk * 4 + j, k = nf * 16 + lr;
        pw[ql * 64 + (((k >> 3) ^ (ql & 7)) * 8) + (k & 7)] = f2bf(s[nf][j]);
      }
    bf16x8 pa[2];
    #pragma unroll
    for (int kf = 0; kf < 2; ++kf) {
      int g = (kf * 4 + lk) ^ (lr & 7);
      pa[kf] = *(const bf16x8*)(pw + lr * 64 + g * 8);
    }
    __builtin_amdgcn_s_setprio(1);
    #pragma unroll
    for (int kf = 0; kf < 2; ++kf)
      #pragma unroll
      for (int nf = 0; nf < 4; ++nf) {
        int d = nf * 16 + lr;
        int g = (kf * 4 + lk) ^ (d & 7);
        bf16x8 bv = *(const bf16x8*)(&Vts[p][d * 64 + g * 8]);
        o[nf] = __builtin_amdgcn_mfma_f32_16x16x32_bf16(pa[kf], bv, o[nf], 0, 0, 0);
      }
    __builtin_amdgcn_s_setprio(0);
    __syncthreads();   // drains next-tile stage + WAR for buf p
  }

  #pragma unroll
  for (int j = 0; j < 4; ++j) lrow[j] = 1.f / lrow[j];
  #pragma unroll
  for (int nf = 0; nf < 4; ++nf)
    #pragma unroll
    for (int j = 0; j < 4; ++j) {
      size_t oidx = ((size_t)(b * Tv + qb + w * 16 + lk * 4 + j)) * Dv + h * HDv + nf * 16 + lr;
      y[oidx] = __float2bfloat16(o[nf][j] * lrow[j]);
    }
}

extern "C" void kernel_launch(void* const* d_in, const int* in_sizes, int n_in,
                              void* d_out, int out_size, void* d_ws, size_t ws_size,
                              hipStream_t stream) {
  const int*   idx      = (const int*)  d_in[0];
  const float* wte      = (const float*)d_in[1];
  const float* wpe      = (const float*)d_in[2];
  const float* ln1_w    = (const float*)d_in[3];
  const float* ln1_b    = (const float*)d_in[4];
  const float* attn_w   = (const float*)d_in[5];
  const float* attn_b   = (const float*)d_in[6];
  const float* proj_w   = (const float*)d_in[7];
  const float* proj_b   = (const float*)d_in[8];
  const float* ln2_w    = (const float*)d_in[9];
  const float* ln2_b    = (const float*)d_in[10];
  const float* fc_w     = (const float*)d_in[11];
  const float* fc_b     = (const float*)d_in[12];
  const float* fcproj_w = (const float*)d_in[13];
  const float* fcproj_b = (const float*)d_in[14];
  const float* lnf_w    = (const float*)d_in[15];
  const float* lnf_b    = (const float*)d_in[16];
  const float* head_w   = (const float*)d_in[17];
  float* outp = (float*)d_out;

  char* w8 = (char*)d_ws;
  float*          x    = (float*)w8;                          // 2048*768 f32
  __hip_bfloat16* h    = (__hip_bfloat16*)(w8 + 6291456);     // 2048*768 bf16
  __hip_bfloat16* qkv  = (__hip_bfloat16*)(w8 + 9437184);     // 2048*2304 bf16
  __hip_bfloat16* m4   = qkv;                                 // 2048*3072 bf16 alias
  __hip_bfloat16* y    = (__hip_bfloat16*)(w8 + 22020096);    // 2048*768 bf16
  __hip_bfloat16* vt   = (__hip_bfloat16*)(w8 + 25165824);    // B*H*64*1024 bf16
  __hip_bfloat16* wbuf = (__hip_bfloat16*)(w8 + 28311552);    // weight staging

  __hip_bfloat16* wb_attn   = wbuf;
  __hip_bfloat16* wb_proj   = wb_attn + (size_t)768 * 2304;
  __hip_bfloat16* wb_fc     = wb_proj + (size_t)768 * 768;
  __hip_bfloat16* wb_fcproj = wb_fc   + (size_t)768 * 3072;

  embed_kernel<<<(MROWS * Dv / 4 + 255) / 256, 256, 0, stream>>>(idx, wte, wpe, x);

  for (int l = 0; l < Lv; ++l) {
    ln_tcast4_kernel<<<MROWS + 6912, 256, 0, stream>>>(
        x, ln1_w + (size_t)l * Dv, ln1_b + (size_t)l * Dv, h,
        attn_w   + (size_t)l * Dv * 3 * Dv,
        proj_w   + (size_t)l * Dv * Dv,
        fc_w     + (size_t)l * Dv * 4 * Dv,
        fcproj_w + (size_t)l * 4 * Dv * Dv,
        wb_attn, wb_proj, wb_fc, wb_fcproj);
    qkv_gemm_kernel<<<dim3(MROWS / 128, 3 * Dv / 64), 256, 0, stream>>>(
        h, wb_attn, attn_b + (size_t)l * 3 * Dv, qkv, vt, MROWS, 3 * Dv, Dv);
    attn_kernel<<<(Tv / 64) * Hv * Bv, 256, 0, stream>>>(qkv, vt, y);
    proj_gemm_kernel<<<dim3(MROWS / 64, Dv / 64), 256, 0, stream>>>(
        y, wb_proj, proj_b + (size_t)l * Dv, x, x, MROWS, Dv, Dv);
    ln_kernel<<<MROWS, 256, 0, stream>>>(x, ln2_w + (size_t)l * Dv, ln2_b + (size_t)l * Dv, h);
    fc_gemm_kernel<<<dim3(MROWS / 128, 4 * Dv / 64), 256, 0, stream>>>(
        h, wb_fc, fc_b + (size_t)l * 4 * Dv, m4, MROWS, 4 * Dv, Dv);
    fcproj_gemm_kernel<<<dim3(MROWS / 64, Dv / 64), 256, 0, stream>>>(
        m4, wb_fcproj, fcproj_b + (size_t)l * Dv, x, x, MROWS, Dv, 4 * Dv);
  }

  lnf_tcast_kernel<<<MROWS + 24000, 256, 0, stream>>>(
      x, lnf_w, lnf_b, h, head_w, wbuf);
  gemm256_kernel<<<dim3(MROWS / 256, Vv / 256), 512, 0, stream>>>(
      h, wbuf, outp, Vv, Dv);
}